// Round 12
// baseline (377.193 us; speedup 1.0000x reference)
//
#include <hip/hip_runtime.h>

#define LTOT 13824          // 24*24*24
#define NCH 144             // scan chunks
#define CHL 96              // chunk length (144*96 = 13824)
#define EPSF 1e-5f

// ---------- workspace layout (floats) ----------
static const size_t OFF_U   = 1024;                 // conv out; DEAD after inproj
static const size_t NU      = (size_t)3*LTOT*64;    // 2654208
static const size_t NXI     = (size_t)3*LTOT*128;   // 5308416
static const size_t NBM     = (size_t)3*LTOT*16;    // 663552
static const size_t NAG     = (size_t)3*NCH*128*16; // 884736
static const size_t OFF_XIT = OFF_U   + NU;         // xiT[(r*128+i)][l]
static const size_t OFF_SZT = OFF_XIT + NXI;        // szT -> becomes yT in-place
static const size_t OFF_DTT = OFF_SZT + NXI;        // dtT[(r*128+i)][l]
static const size_t OFF_BMT = OFF_DTT + NXI;        // BmT[(r*16+n)][l]
static const size_t OFF_CMT = OFF_BMT + NBM;
static const size_t OFF_W2  = OFF_CMT + NBM;        // 384*64
static const size_t OFF_WT  = OFF_W2 + 24576;       // 3*192*64 transposed conv weights
static const size_t OFF_WI  = OFF_WT + 36864;       // in_proj weights transposed [q][col] 64*256
// scan scratch overlaid on dead U region (3*NAG = 2654208 = NU exactly)
static const size_t OFF_AGA = OFF_U;
static const size_t OFF_AGB = OFF_U + NAG;
static const size_t OFF_SEED= OFF_U + 2*NAG;
static const size_t OFF_FIN = OFF_DTT;              // dtT dead after scan3

__device__ __forceinline__ float sigm(float x){ return 1.f/(1.f+__expf(-x)); }
__device__ __forceinline__ float siluf(float x){ return x*sigm(x); }
__device__ __forceinline__ float softplusf(float x){
    return fmaxf(x,0.f) + log1pf(__expf(-fabsf(x)));
}

// all-VALU cross-lane adds via DPP (no LDS pipe)
template<int CTRL>
__device__ __forceinline__ float dpp_add(float x){
    int v = __builtin_amdgcn_update_dpp(0, __float_as_int(x), CTRL, 0xf, 0xf, true);
    return x + __int_as_float(v);
}
__device__ __forceinline__ float sum16(float x){   // sum within each 16-lane row
    x = dpp_add<0xB1>(x);    // quad_perm xor1
    x = dpp_add<0x4E>(x);    // quad_perm xor2
    x = dpp_add<0x141>(x);   // row_half_mirror
    x = dpp_add<0x140>(x);   // row_mirror
    return x;
}

// ===== K0: weight prep — conv transpose, out_proj∘conv fusion, in_proj^T ===
__global__ __launch_bounds__(256) void k_prep(const float* __restrict__ w1,
                      const float* __restrict__ w2, const float* __restrict__ w3,
                      const float* __restrict__ opw, const float* __restrict__ wf,
                      const float* __restrict__ ipw,
                      float* __restrict__ wt, float* __restrict__ w2t,
                      float* __restrict__ wi)
{
    if (blockIdx.x < 144){
        int idx = blockIdx.x*256 + threadIdx.x;      // 0..36863
        int r = idx / 12288, rem = idx % 12288;
        int k = rem >> 6, o = rem & 63;
        const float* W = (r==0)?w1:(r==1)?w2:w3;
        wt[idx] = W[o*192 + k];
    } else if (blockIdx.x < 240){
        int idx = (blockIdx.x-144)*256 + threadIdx.x; // 0..24575
        int o = idx & 63, ri = idx >> 6;
        int r = ri >> 7, i = ri & 127;
        float acc = 0.f;
        for (int c2=0;c2<64;c2++)
            acc += opw[c2*128+i] * wf[o*192 + r*64 + c2];
        w2t[idx] = acc;
    } else {
        int idx = (blockIdx.x-240)*256 + threadIdx.x; // 0..16383
        int col = idx & 255, q = idx >> 8;
        wi[q*256 + col] = ipw[col*64 + q];
    }
}

// ======= K1: axis conv — 2 rows/block, 4o x 4w, VMEM weights, async-stage ==
// 192 thr = 2 rows x (16og x 6wg); grid (288,3). Stage ph+1 loads under ph.
__global__ __launch_bounds__(192) void k_conv(const float* __restrict__ x,
                       const float* __restrict__ wt,
                       const float* __restrict__ b1, const float* __restrict__ b2,
                       const float* __restrict__ b3,
                       float* __restrict__ u, float* __restrict__ ws)
{
    __shared__ __align__(16) float xs[2*1152];  // x tile only, 9.2 KB
    __shared__ float ssum[64], ssq[64];
    const int r = blockIdx.y;
    const int row0 = blockIdx.x*2;
    const float* Bz = (r==0)?b1:(r==1)?b2:b3;
    const int tid = threadIdx.x;

    if (tid < 64){ ssum[tid]=0.f; ssq[tid]=0.f; }

    const int rw = (tid >= 96) ? 1 : 0, t2 = tid - rw*96;
    const int og = t2 & 15, wg2 = t2 >> 4;      // 16 og x 6 wg
    const int o0 = og*4, w0 = wg2*4;
    float acc[4][4];
    {
        float b0 = Bz[o0], b1v = Bz[o0+1], b2v = Bz[o0+2], b3v = Bz[o0+3];
        #pragma unroll
        for (int wj=0;wj<4;wj++){ acc[0][wj]=b0; acc[1][wj]=b1v; acc[2][wj]=b2v; acc[3][wj]=b3v; }
    }

    // precompute the 12 staging-slot addresses (ph-invariant; ph adds 16*LTOT)
    int sa[12];
    #pragma unroll
    for (int j=0;j<12;j++){
        int f = tid + j*192;               // 0..2303 = rw2*1152 + s
        int rw2 = f / 1152, s = f - rw2*1152;
        int w = s % 24; int kt = s / 24; int ic2 = kt/3, t = kt%3;
        int rr = row0 + rw2;
        int d = rr/24, h = rr%24;
        int src = 0; bool valid = true;
        if (r==0){ int dd = d+t-1; valid = (dd>=0 && dd<24); src = (dd*24+h)*24 + w; }
        else if (r==1){ int hh = h+t-1; valid = (hh>=0 && hh<24); src = (d*24+hh)*24 + w; }
        else { int ww = w+t-1; valid = (ww>=0 && ww<24); src = rr*24 + ww; }
        sa[j] = valid ? (ic2*LTOT + src) : -1;
    }

    const float* xrow = &xs[rw*1152];
    const float* wbase = wt + (size_t)r*12288 + o0;  // per-lane VMEM path

    float rs[12];
    #pragma unroll
    for (int j=0;j<12;j++) rs[j] = (sa[j] >= 0) ? x[sa[j]] : 0.f;

    for (int ph=0; ph<4; ph++){
        __syncthreads();                     // xs free (prev compute done)
        #pragma unroll
        for (int j=0;j<12;j++) xs[tid + j*192] = rs[j];
        if (ph < 3){
            const float* xp = x + (size_t)(ph+1)*16*LTOT;
            #pragma unroll
            for (int j=0;j<12;j++) rs[j] = (sa[j] >= 0) ? xp[sa[j]] : 0.f;
        }
        __syncthreads();                     // xs ready

        for (int sub=0; sub<3; sub++){
            const float* wp = wbase + (size_t)(ph*48 + sub*16)*64;
            float4 wreg[16];
            #pragma unroll
            for (int kk=0;kk<16;kk++)
                wreg[kk] = *(const float4*)&wp[(size_t)kk*64];
            #pragma unroll
            for (int kk=0;kk<16;kk++){
                float4 wv = wreg[kk];
                float4 xv = *(const float4*)&xrow[(sub*16+kk)*24 + w0];
                acc[0][0]=fmaf(wv.x,xv.x,acc[0][0]); acc[0][1]=fmaf(wv.x,xv.y,acc[0][1]);
                acc[0][2]=fmaf(wv.x,xv.z,acc[0][2]); acc[0][3]=fmaf(wv.x,xv.w,acc[0][3]);
                acc[1][0]=fmaf(wv.y,xv.x,acc[1][0]); acc[1][1]=fmaf(wv.y,xv.y,acc[1][1]);
                acc[1][2]=fmaf(wv.y,xv.z,acc[1][2]); acc[1][3]=fmaf(wv.y,xv.w,acc[1][3]);
                acc[2][0]=fmaf(wv.z,xv.x,acc[2][0]); acc[2][1]=fmaf(wv.z,xv.y,acc[2][1]);
                acc[2][2]=fmaf(wv.z,xv.z,acc[2][2]); acc[2][3]=fmaf(wv.z,xv.w,acc[2][3]);
                acc[3][0]=fmaf(wv.w,xv.x,acc[3][0]); acc[3][1]=fmaf(wv.w,xv.y,acc[3][1]);
                acc[3][2]=fmaf(wv.w,xv.z,acc[3][2]); acc[3][3]=fmaf(wv.w,xv.w,acc[3][3]);
            }
        }
    }

    size_t ub = ((size_t)r*LTOT + (size_t)(row0+rw)*24)*64;
    float ps[4]={0,0,0,0}, pq[4]={0,0,0,0};
    #pragma unroll
    for (int wj=0; wj<4; wj++){
        float4 v = make_float4(acc[0][wj],acc[1][wj],acc[2][wj],acc[3][wj]);
        *(float4*)&u[ub + (size_t)(w0+wj)*64 + o0] = v;
        ps[0]+=v.x; pq[0]+=v.x*v.x; ps[1]+=v.y; pq[1]+=v.y*v.y;
        ps[2]+=v.z; pq[2]+=v.z*v.z; ps[3]+=v.w; pq[3]+=v.w*v.w;
    }
    #pragma unroll
    for (int oj=0;oj<4;oj++){
        atomicAdd(&ssum[o0+oj], ps[oj]);
        atomicAdd(&ssq[o0+oj], pq[oj]);
    }
    __syncthreads();
    if (tid < 64){
        atomicAdd(&ws[r*64 + tid], ssum[tid]);
        atomicAdd(&ws[192 + r*64 + tid], ssq[tid]);
    }
}

// ================= K2: finalize branch IN stats ============================
__global__ __launch_bounds__(192) void k_stats1(float* ws){
    int t = threadIdx.x;   // 0..191
    float s = ws[t], q = ws[192+t];
    float m = s*(1.f/(float)LTOT);
    float v = q*(1.f/(float)LTOT) - m*m;
    ws[512+t] = m; ws[704+t] = rsqrtf(v + EPSF);
}

// == K4: fused IN+ReLU+LN + in_proj — 8o x 4p tile, weights in VGPR (VMEM) ==
__global__ __launch_bounds__(256, 2) void k_inproj(const float* __restrict__ u, float* __restrict__ xiT,
                         float* __restrict__ szT, const float* __restrict__ wi,
                         const float* __restrict__ cw, const float* __restrict__ cb,
                         const float* __restrict__ ws,
                         const float* g1,const float* be1,const float* g2,const float* be2,
                         const float* g3,const float* be3,
                         const float* lnw,const float* lnb)
{
    __shared__ float xl[64*65];                 // [c][p] padded, 16.6 KB
    const int tid = threadIdx.x, r = blockIdx.y;
    const int lane = tid & 63;
    const int wv = __builtin_amdgcn_readfirstlane(tid >> 6);
    const int l0 = blockIdx.x*64;
    size_t gbase = (size_t)r*LTOT + l0;

    {
        const float* g  = (r==0)?g1:(r==1)?g2:g3;
        const float* be = (r==0)?be1:(r==1)?be2:be3;
        float m  = ws[512 + r*64 + lane], rs = ws[704 + r*64 + lane];
        float gg = g[lane], bb = be[lane];
        float lw = lnw[lane], lb = lnb[lane];
        for (int j=0;j<16;j++){
            int p = wv*16 + j;
            float vv = u[(gbase+p)*64 + lane];
            vv = fmaxf((vv-m)*rs*gg + bb, 0.f);
            float s1 = sum16(vv), s2 = sum16(vv*vv);
            s1 += __shfl_xor(s1,16); s2 += __shfl_xor(s2,16);
            s1 += __shfl_xor(s1,32); s2 += __shfl_xor(s2,32);
            float mean = s1*(1.f/64.f);
            float var  = s2*(1.f/64.f) - mean*mean;
            xl[lane*65 + p] = (vv-mean)*rsqrtf(var+EPSF)*lw + lb;
        }
    }
    __syncthreads();

    const int pq = tid & 15, oq = tid >> 4;     // 16 p-quads x 16 o-groups
    const int p0 = pq*4;

    #pragma unroll 1
    for (int ch=0; ch<2; ch++){
        const int c0 = ch*128 + oq*8;
        float acc[8][4];
        #pragma unroll
        for (int oj=0;oj<8;oj++){ acc[oj][0]=0.f; acc[oj][1]=0.f; acc[oj][2]=0.f; acc[oj][3]=0.f; }

        for (int sub=0; sub<8; sub++){
            float4 wa[8], wb[8];
            #pragma unroll
            for (int qq=0;qq<8;qq++){
                const float* wp = wi + (size_t)(sub*8+qq)*256 + c0;
                wa[qq] = *(const float4*)wp;
                wb[qq] = *(const float4*)(wp+4);
            }
            #pragma unroll
            for (int qq=0;qq<8;qq++){
                float4 x4 = *(const float4*)&xl[(sub*8+qq)*65 + p0];
                float4 a = wa[qq], b = wb[qq];
                acc[0][0]=fmaf(a.x,x4.x,acc[0][0]); acc[0][1]=fmaf(a.x,x4.y,acc[0][1]);
                acc[0][2]=fmaf(a.x,x4.z,acc[0][2]); acc[0][3]=fmaf(a.x,x4.w,acc[0][3]);
                acc[1][0]=fmaf(a.y,x4.x,acc[1][0]); acc[1][1]=fmaf(a.y,x4.y,acc[1][1]);
                acc[1][2]=fmaf(a.y,x4.z,acc[1][2]); acc[1][3]=fmaf(a.y,x4.w,acc[1][3]);
                acc[2][0]=fmaf(a.z,x4.x,acc[2][0]); acc[2][1]=fmaf(a.z,x4.y,acc[2][1]);
                acc[2][2]=fmaf(a.z,x4.z,acc[2][2]); acc[2][3]=fmaf(a.z,x4.w,acc[2][3]);
                acc[3][0]=fmaf(a.w,x4.x,acc[3][0]); acc[3][1]=fmaf(a.w,x4.y,acc[3][1]);
                acc[3][2]=fmaf(a.w,x4.z,acc[3][2]); acc[3][3]=fmaf(a.w,x4.w,acc[3][3]);
                acc[4][0]=fmaf(b.x,x4.x,acc[4][0]); acc[4][1]=fmaf(b.x,x4.y,acc[4][1]);
                acc[4][2]=fmaf(b.x,x4.z,acc[4][2]); acc[4][3]=fmaf(b.x,x4.w,acc[4][3]);
                acc[5][0]=fmaf(b.y,x4.x,acc[5][0]); acc[5][1]=fmaf(b.y,x4.y,acc[5][1]);
                acc[5][2]=fmaf(b.y,x4.z,acc[5][2]); acc[5][3]=fmaf(b.y,x4.w,acc[5][3]);
                acc[6][0]=fmaf(b.z,x4.x,acc[6][0]); acc[6][1]=fmaf(b.z,x4.y,acc[6][1]);
                acc[6][2]=fmaf(b.z,x4.z,acc[6][2]); acc[6][3]=fmaf(b.z,x4.w,acc[6][3]);
                acc[7][0]=fmaf(b.w,x4.x,acc[7][0]); acc[7][1]=fmaf(b.w,x4.y,acc[7][1]);
                acc[7][2]=fmaf(b.w,x4.z,acc[7][2]); acc[7][3]=fmaf(b.w,x4.w,acc[7][3]);
            }
        }

        if (ch == 0){
            #pragma unroll
            for (int oj=0;oj<8;oj++){
                int c = c0 + oj;
                float cwv = cw[c], cbv = cb[c];
                float4 v = make_float4(
                    siluf(fmaf(acc[oj][0], cwv, cbv)),
                    siluf(fmaf(acc[oj][1], cwv, cbv)),
                    siluf(fmaf(acc[oj][2], cwv, cbv)),
                    siluf(fmaf(acc[oj][3], cwv, cbv)));
                *(float4*)&xiT[((size_t)r*128 + c)*LTOT + l0 + p0] = v;
            }
        } else {
            #pragma unroll
            for (int oj=0;oj<8;oj++){
                int c = c0 - 128 + oj;
                float4 v = make_float4(siluf(acc[oj][0]), siluf(acc[oj][1]),
                                       siluf(acc[oj][2]), siluf(acc[oj][3]));
                *(float4*)&szT[((size_t)r*128 + c)*LTOT + l0 + p0] = v;
            }
        }
    }
}

// ================= K5: x_proj + dt softplus -> transposed rows =============
__global__ __launch_bounds__(256) void k_xproj(const float* __restrict__ xiT, float* __restrict__ dtT,
                        float* __restrict__ BmT, float* __restrict__ CmT,
                        const float* __restrict__ xpw, const float* __restrict__ dtw,
                        const float* __restrict__ dtb)
{
    __shared__ __align__(16) float xt[128*36];   // [c*36 + p]
    __shared__ float ww[36*129];                 // [k*129 + c]
    __shared__ float sd[4*36];                   // dt-rank rows [k*36 + p]
    const int tid = threadIdx.x, r = blockIdx.y;
    const int l0 = blockIdx.x*32;

    for (int s = tid; s < 4096; s += 256){
        int c = s>>5, p = s&31;
        xt[c*36+p] = xiT[((size_t)r*128 + c)*LTOT + l0 + p];
    }
    for (int s = tid; s < 4608; s += 256){
        int k = s>>7, c = s&127;
        ww[k*129+c] = xpw[s];
    }
    __syncthreads();

    const int wv = tid>>6, lane = tid&63;
    float acc[8] = {0,0,0,0,0,0,0,0};
    if (lane < 36){
        const float* wrow = &ww[lane*129];
        for (int c=0;c<128;c++){
            float w = wrow[c];
            float4 a = *(const float4*)&xt[c*36 + wv*8];
            float4 b = *(const float4*)&xt[c*36 + wv*8 + 4];
            acc[0]=fmaf(w,a.x,acc[0]); acc[1]=fmaf(w,a.y,acc[1]);
            acc[2]=fmaf(w,a.z,acc[2]); acc[3]=fmaf(w,a.w,acc[3]);
            acc[4]=fmaf(w,b.x,acc[4]); acc[5]=fmaf(w,b.y,acc[5]);
            acc[6]=fmaf(w,b.z,acc[6]); acc[7]=fmaf(w,b.w,acc[7]);
        }
    }
    if (lane>=4 && lane<36){
        float* dst = (lane<20) ? BmT : CmT;
        int n = (lane<20) ? (lane-4) : (lane-20);
        size_t base = ((size_t)r*16 + n)*LTOT + l0 + wv*8;
        *(float4*)&dst[base]   = make_float4(acc[0],acc[1],acc[2],acc[3]);
        *(float4*)&dst[base+4] = make_float4(acc[4],acc[5],acc[6],acc[7]);
    }
    if (lane < 4){
        #pragma unroll
        for (int p=0;p<8;p++) sd[lane*36 + wv*8 + p] = acc[p];
    }
    __syncthreads();

    const int i = tid>>1, ph = tid&1;
    float4 dw = *(const float4*)&dtw[i*4];
    float db = dtb[i];
    float buf[16];
    #pragma unroll
    for (int t=0;t<16;t++){
        int p = ph*16 + t;
        float v = db + dw.x*sd[0*36+p] + dw.y*sd[1*36+p]
                     + dw.z*sd[2*36+p] + dw.w*sd[3*36+p];
        buf[t] = softplusf(v);
    }
    size_t base = ((size_t)r*128 + i)*LTOT + l0 + ph*16;
    #pragma unroll
    for (int q=0;q<4;q++){
        *(float4*)&dtT[base + 4*q] =
            make_float4(buf[4*q], buf[4*q+1], buf[4*q+2], buf[4*q+3]);
    }
}

// ===== K6: scan pass 1 — CHL=96, async-staged halves, 3 blk/CU reg budget ==
__global__ __launch_bounds__(256, 3) void k_scan1(const float* __restrict__ dtT, const float* __restrict__ BmT,
                        const float* __restrict__ xiT, const float* __restrict__ Alog,
                        float* __restrict__ aga, float* __restrict__ agb)
{
    __shared__ __align__(16) float sdt[64*52];   // 13.3 KB, stride 52
    __shared__ __align__(16) float sxi[64*52];   // 13.3 KB
    __shared__ __align__(16) float sbm[16*52];   //  3.3 KB  -> 29.9 KB total
    const int tid = threadIdx.x;
    const int ng = tid & 3, il = tid >> 2;       // quad = 4 states, il = channel 0..63
    const int c = blockIdx.x, ib = blockIdx.y, r = blockIdx.z;
    const int i = ib*64 + il;

    float A2[4];
    #pragma unroll
    for (int k=0;k<4;k++) A2[k] = -expf(Alog[i*16 + ng*4 + k]) * 1.44269504f;

    const size_t rowDX = ((size_t)r*128 + ib*64)*LTOT + (size_t)c*CHL;
    const size_t rowB  = ((size_t)r*16)*LTOT + (size_t)c*CHL;

    // per-thread staging slots: dt/xi f = tid + j*256 (j<3); B: tid<192
    int rw_[3], tq_[3];
    #pragma unroll
    for (int j=0;j<3;j++){ int f = tid + j*256; rw_[j] = f/12; tq_[j] = f%12; }
    const int brow = tid/12, bt4 = tid%12;

    float4 rdt[3], rxi[3], rbm;
    #pragma unroll
    for (int j=0;j<3;j++){
        size_t g = rowDX + (size_t)rw_[j]*LTOT + tq_[j]*4;
        rdt[j] = *(const float4*)&dtT[g];
        rxi[j] = *(const float4*)&xiT[g];
    }
    if (tid < 192) rbm = *(const float4*)&BmT[rowB + (size_t)brow*LTOT + bt4*4];

    float b0=0.f,b1=0.f,b2=0.f,b3=0.f, dsum=0.f;

    for (int hh=0; hh<2; hh++){
        __syncthreads();                         // prev compute done; LDS free
        #pragma unroll
        for (int j=0;j<3;j++){
            *(float4*)&sdt[rw_[j]*52 + tq_[j]*4] = rdt[j];
            *(float4*)&sxi[rw_[j]*52 + tq_[j]*4] = rxi[j];
        }
        if (tid < 192) *(float4*)&sbm[brow*52 + bt4*4] = rbm;
        if (hh == 0){                            // prefetch half 1 under compute
            #pragma unroll
            for (int j=0;j<3;j++){
                size_t g = rowDX + (size_t)rw_[j]*LTOT + 48 + tq_[j]*4;
                rdt[j] = *(const float4*)&dtT[g];
                rxi[j] = *(const float4*)&xiT[g];
            }
            if (tid < 192) rbm = *(const float4*)&BmT[rowB + (size_t)brow*LTOT + 48 + bt4*4];
        }
        __syncthreads();                         // LDS ready

        for (int t4 = 0; t4 < 12; t4++){
            float4 d4 = *(const float4*)&sdt[il*52 + t4*4];
            float4 x4 = *(const float4*)&sxi[il*52 + t4*4];
            float4 B0 = *(const float4*)&sbm[(ng*4+0)*52 + t4*4];
            float4 B1 = *(const float4*)&sbm[(ng*4+1)*52 + t4*4];
            float4 B2 = *(const float4*)&sbm[(ng*4+2)*52 + t4*4];
            float4 B3 = *(const float4*)&sbm[(ng*4+3)*52 + t4*4];
            #define S1Q(dv,xv,c0,c1,c2,c3) { \
                float dx = (dv)*(xv); dsum += (dv); \
                b0 = fmaf(exp2f(A2[0]*(dv)), b0, dx*(c0)); \
                b1 = fmaf(exp2f(A2[1]*(dv)), b1, dx*(c1)); \
                b2 = fmaf(exp2f(A2[2]*(dv)), b2, dx*(c2)); \
                b3 = fmaf(exp2f(A2[3]*(dv)), b3, dx*(c3)); }
            S1Q(d4.x, x4.x, B0.x, B1.x, B2.x, B3.x)
            S1Q(d4.y, x4.y, B0.y, B1.y, B2.y, B3.y)
            S1Q(d4.z, x4.z, B0.z, B1.z, B2.z, B3.z)
            S1Q(d4.w, x4.w, B0.w, B1.w, B2.w, B3.w)
            #undef S1Q
        }
    }

    size_t o = ((size_t)(r*NCH+c)*128 + i)*16 + ng*4;
    *(float4*)&aga[o] = make_float4(exp2f(A2[0]*dsum), exp2f(A2[1]*dsum),
                                    exp2f(A2[2]*dsum), exp2f(A2[3]*dsum));
    *(float4*)&agb[o] = make_float4(b0,b1,b2,b3);
}

// ================= K7: scan pass 2 — combine chunk aggregates ==============
__global__ __launch_bounds__(512) void k_scan2(const float* __restrict__ aga, const float* __restrict__ agb,
                        float* __restrict__ seed)
{
    int t = blockIdx.x*512 + threadIdx.x;  // 0..6143
    int r = t >> 11, rem = t & 2047;
    float h = 0.f;
    for (int c=0;c<NCH;c++){
        size_t idx = (size_t)(r*NCH+c)*2048 + rem;
        float a = aga[idx], b = agb[idx];
        seed[idx] = h;
        h = fmaf(a, h, b);
    }
}

// ===== K8: scan pass 3 — CHL=96, async-staged halves, 3 blk/CU reg budget ==
__global__ __launch_bounds__(256, 3) void k_scan3(const float* __restrict__ dtT, const float* __restrict__ BmT,
                        const float* __restrict__ CmT, const float* __restrict__ xiT,
                        float* __restrict__ szT, const float* __restrict__ Alog,
                        const float* __restrict__ Dp, const float* __restrict__ seed)
{
    __shared__ __align__(16) float sdt[64*52];   // 13.3 KB; y_raw overwrites in place
    __shared__ __align__(16) float sxi[64*52];   // 13.3 KB
    __shared__ __align__(16) float sbm[16*52];   //  3.3 KB
    __shared__ __align__(16) float scm[16*52];   //  3.3 KB  -> 32.5 KB total
    const int tid = threadIdx.x;
    const int ng = tid & 3, il = tid >> 2;
    const int c = blockIdx.x, ib = blockIdx.y, r = blockIdx.z;
    const int i = ib*64 + il;

    float A2[4];
    #pragma unroll
    for (int k=0;k<4;k++) A2[k] = -expf(Alog[i*16 + ng*4 + k]) * 1.44269504f;
    const float Dv = Dp[i];

    float4 h4 = *(const float4*)&seed[((size_t)(r*NCH+c)*128 + i)*16 + ng*4];
    float h0=h4.x, h1=h4.y, h2=h4.z, h3=h4.w;

    const size_t rowDX = ((size_t)r*128 + ib*64)*LTOT + (size_t)c*CHL;
    const size_t rowB  = ((size_t)r*16)*LTOT + (size_t)c*CHL;

    // per-thread staging slots
    int rw_[3], tq_[3];
    #pragma unroll
    for (int j=0;j<3;j++){ int f = tid + j*256; rw_[j] = f/12; tq_[j] = f%12; }
    // B/C slot 0: all threads (tid<192 -> B, else C); slot 1: tid<128 -> C
    const bool a0isB = (tid < 192);
    const int a0f = a0isB ? tid : (tid - 192);
    const int a0row = a0f/12, a0t4 = a0f%12;
    const int a1f = tid + 64;                    // for tid<128: arr=1, f2=tid+64
    const int a1row = a1f/12, a1t4 = a1f%12;

    float4 rdt[3], rxi[3], rb0, rb1;
    #pragma unroll
    for (int j=0;j<3;j++){
        size_t g = rowDX + (size_t)rw_[j]*LTOT + tq_[j]*4;
        rdt[j] = *(const float4*)&dtT[g];
        rxi[j] = *(const float4*)&xiT[g];
    }
    {
        const float* src0 = a0isB ? BmT : CmT;
        rb0 = *(const float4*)&src0[rowB + (size_t)a0row*LTOT + a0t4*4];
        if (tid < 128) rb1 = *(const float4*)&CmT[rowB + (size_t)a1row*LTOT + a1t4*4];
    }

    for (int hh=0; hh<2; hh++){
        __syncthreads();           // prev write-back reads done; LDS free
        #pragma unroll
        for (int j=0;j<3;j++){
            *(float4*)&sdt[rw_[j]*52 + tq_[j]*4] = rdt[j];
            *(float4*)&sxi[rw_[j]*52 + tq_[j]*4] = rxi[j];
        }
        {
            float* dst0 = a0isB ? sbm : scm;
            *(float4*)&dst0[a0row*52 + a0t4*4] = rb0;
            if (tid < 128) *(float4*)&scm[a1row*52 + a1t4*4] = rb1;
        }
        if (hh == 0){              // prefetch half 1; rides out under compute
            #pragma unroll
            for (int j=0;j<3;j++){
                size_t g = rowDX + (size_t)rw_[j]*LTOT + 48 + tq_[j]*4;
                rdt[j] = *(const float4*)&dtT[g];
                rxi[j] = *(const float4*)&xiT[g];
            }
            const float* src0 = a0isB ? BmT : CmT;
            rb0 = *(const float4*)&src0[rowB + (size_t)a0row*LTOT + 48 + a0t4*4];
            if (tid < 128) rb1 = *(const float4*)&CmT[rowB + (size_t)a1row*LTOT + 48 + a1t4*4];
        }
        __syncthreads();           // LDS ready

        for (int t4 = 0; t4 < 12; t4++){
            float4 d4 = *(const float4*)&sdt[il*52 + t4*4];
            float4 x4 = *(const float4*)&sxi[il*52 + t4*4];
            float4 B0 = *(const float4*)&sbm[(ng*4+0)*52 + t4*4];
            float4 B1 = *(const float4*)&sbm[(ng*4+1)*52 + t4*4];
            float4 B2 = *(const float4*)&sbm[(ng*4+2)*52 + t4*4];
            float4 B3 = *(const float4*)&sbm[(ng*4+3)*52 + t4*4];
            float4 C0 = *(const float4*)&scm[(ng*4+0)*52 + t4*4];
            float4 C1 = *(const float4*)&scm[(ng*4+1)*52 + t4*4];
            float4 C2 = *(const float4*)&scm[(ng*4+2)*52 + t4*4];
            float4 C3 = *(const float4*)&scm[(ng*4+3)*52 + t4*4];
            float4 y4;
            #define S3Q(dv,xv,b0c,b1c,b2c,b3c,c0c,c1c,c2c,c3c,oy) { \
                float dx = (dv)*(xv); \
                h0 = fmaf(exp2f(A2[0]*(dv)), h0, dx*(b0c)); \
                h1 = fmaf(exp2f(A2[1]*(dv)), h1, dx*(b1c)); \
                h2 = fmaf(exp2f(A2[2]*(dv)), h2, dx*(b2c)); \
                h3 = fmaf(exp2f(A2[3]*(dv)), h3, dx*(b3c)); \
                float p = h0*(c0c); p = fmaf(h1,(c1c),p); \
                p = fmaf(h2,(c2c),p); p = fmaf(h3,(c3c),p); \
                p = dpp_add<0xB1>(p); p = dpp_add<0x4E>(p); \
                oy = fmaf((xv), Dv, p); }
            S3Q(d4.x,x4.x, B0.x,B1.x,B2.x,B3.x, C0.x,C1.x,C2.x,C3.x, y4.x)
            S3Q(d4.y,x4.y, B0.y,B1.y,B2.y,B3.y, C0.y,C1.y,C2.y,C3.y, y4.y)
            S3Q(d4.z,x4.z, B0.z,B1.z,B2.z,B3.z, C0.z,C1.z,C2.z,C3.z, y4.z)
            S3Q(d4.w,x4.w, B0.w,B1.w,B2.w,B3.w, C0.w,C1.w,C2.w,C3.w, y4.w)
            #undef S3Q
            if (ng == 0) *(float4*)&sdt[il*52 + t4*4] = y4;   // y_raw into consumed dt slot
        }
        __syncthreads();

        // coalesced write-back: y_raw * sz -> szT (in place)
        const int lb = hh*48;
        for (int f = tid; f < 768; f += 256){
            int row = f / 12, t4 = f % 12;
            size_t gidx = rowDX + (size_t)row*LTOT + lb + t4*4;
            float4 yv = *(const float4*)&sdt[row*52 + t4*4];
            float4 s  = *(const float4*)&szT[gidx];
            *(float4*)&szT[gidx] = make_float4(yv.x*s.x, yv.y*s.y, yv.z*s.z, yv.w*s.w);
        }
    }
}

// ========== K10: out_proj∘conv GEMM — w fully unrolled into VGPRs ==========
__global__ __launch_bounds__(256, 1) void k_fin(const float* __restrict__ yT, const float* __restrict__ w2t,
                      const float* __restrict__ bfb, float* __restrict__ fin,
                      float* __restrict__ ws)
{
    __shared__ __align__(16) float yl[384*20];  // [k*20 + p], 30.7 KB
    __shared__ float part[4*16*64];             // [sg][p][o], 16 KB
    __shared__ float ssum[64], ssq[64];
    const int tid = threadIdx.x;
    const int l0 = blockIdx.x*16;
    const int o = tid & 63, sg = tid >> 6;

    for (int f = tid; f < 6144; f += 256){
        int k = f >> 4, p = f & 15;
        yl[k*20 + p] = yT[(size_t)k*LTOT + l0 + p];
    }
    float wreg[96];
    {
        const float* wp = w2t + (size_t)(sg*96)*64 + o;
        #pragma unroll
        for (int j=0;j<96;j++) wreg[j] = wp[(size_t)j*64];
    }
    if (tid < 64){ ssum[tid]=0.f; ssq[tid]=0.f; }
    __syncthreads();

    float acc[16];
    #pragma unroll
    for (int p=0;p<16;p++) acc[p]=0.f;
    const float* ylbase = &yl[sg*96*20];
    #pragma unroll
    for (int j=0;j<96;j++){
        float w = wreg[j];
        const float4* yp4 = (const float4*)&ylbase[j*20];
        float4 a = yp4[0], b = yp4[1], c = yp4[2], d = yp4[3];
        acc[0] =fmaf(w,a.x,acc[0]);  acc[1] =fmaf(w,a.y,acc[1]);
        acc[2] =fmaf(w,a.z,acc[2]);  acc[3] =fmaf(w,a.w,acc[3]);
        acc[4] =fmaf(w,b.x,acc[4]);  acc[5] =fmaf(w,b.y,acc[5]);
        acc[6] =fmaf(w,b.z,acc[6]);  acc[7] =fmaf(w,b.w,acc[7]);
        acc[8] =fmaf(w,c.x,acc[8]);  acc[9] =fmaf(w,c.y,acc[9]);
        acc[10]=fmaf(w,c.z,acc[10]); acc[11]=fmaf(w,c.w,acc[11]);
        acc[12]=fmaf(w,d.x,acc[12]); acc[13]=fmaf(w,d.y,acc[13]);
        acc[14]=fmaf(w,d.z,acc[14]); acc[15]=fmaf(w,d.w,acc[15]);
    }
    #pragma unroll
    for (int p=0;p<16;p++) part[(sg*16+p)*64 + o] = acc[p];
    __syncthreads();

    float bias = bfb[o];
    float ps=0.f, pq=0.f;
    #pragma unroll
    for (int j=0;j<4;j++){
        int p = sg + j*4;
        float s = part[(0*16+p)*64+o] + part[(1*16+p)*64+o]
                + part[(2*16+p)*64+o] + part[(3*16+p)*64+o] + bias;
        fin[(size_t)(l0+p)*64 + o] = s;
        ps += s; pq += s*s;
    }
    atomicAdd(&ssum[o], ps); atomicAdd(&ssq[o], pq);
    __syncthreads();
    if (tid<64){
        atomicAdd(&ws[384+tid], ssum[tid]);
        atomicAdd(&ws[448+tid], ssq[tid]);
    }
}

// ================= K11: finalize final IN stats ============================
__global__ __launch_bounds__(64) void k_statsF(float* ws){
    int t = threadIdx.x;  // 0..63
    float s = ws[384+t], q = ws[448+t];
    float m = s*(1.f/(float)LTOT);
    float v = q*(1.f/(float)LTOT) - m*m;
    ws[896+t] = m; ws[960+t] = rsqrtf(v + EPSF);
}

// ================= K12: final IN + ReLU + transpose + fp32 store ===========
__global__ __launch_bounds__(256) void k_out(const float* __restrict__ fin, const float* __restrict__ ws,
                      const float* __restrict__ gf, const float* __restrict__ bef,
                      float* __restrict__ out)
{
    __shared__ float tl[64*65];
    const int tid = threadIdx.x;
    const int l0 = blockIdx.x*64;
    for (int s=tid; s<4096; s+=256){
        int li = s>>6, o = s&63;
        float v = fin[(size_t)(l0+li)*64 + o];
        v = fmaxf((v - ws[896+o])*ws[960+o]*gf[o] + bef[o], 0.f);
        tl[o*65+li] = v;
    }
    __syncthreads();
    for (int s=tid; s<4096; s+=256){
        int o = s>>6, li = s&63;
        out[(size_t)o*LTOT + l0 + li] = tl[o*65+li];
    }
}

extern "C" void kernel_launch(void* const* d_in, const int* in_sizes, int n_in,
                              void* d_out, int out_size, void* d_ws, size_t ws_size,
                              hipStream_t stream)
{
    const float* X    = (const float*)d_in[0];
    const float* W1   = (const float*)d_in[1];  const float* B1  = (const float*)d_in[2];
    const float* G1   = (const float*)d_in[3];  const float* BE1 = (const float*)d_in[4];
    const float* W2   = (const float*)d_in[5];  const float* B2  = (const float*)d_in[6];
    const float* G2   = (const float*)d_in[7];  const float* BE2 = (const float*)d_in[8];
    const float* W3   = (const float*)d_in[9];  const float* B3  = (const float*)d_in[10];
    const float* G3   = (const float*)d_in[11]; const float* BE3 = (const float*)d_in[12];
    const float* LNW  = (const float*)d_in[13]; const float* LNB = (const float*)d_in[14];
    const float* IPW  = (const float*)d_in[15];
    const float* CW   = (const float*)d_in[16]; const float* CB  = (const float*)d_in[17];
    const float* XPW  = (const float*)d_in[18];
    const float* DTW  = (const float*)d_in[19]; const float* DTB = (const float*)d_in[20];
    const float* ALOG = (const float*)d_in[21]; const float* DP  = (const float*)d_in[22];
    const float* OPW  = (const float*)d_in[23];
    const float* WF   = (const float*)d_in[24]; const float* BF  = (const float*)d_in[25];
    const float* GF   = (const float*)d_in[26]; const float* BEF = (const float*)d_in[27];
    float* ws = (float*)d_ws;

    (void)hipMemsetAsync(d_ws, 0, 2048, stream);

    k_prep  <<<304, 256, 0, stream>>>(W1, W2, W3, OPW, WF, IPW,
                                      ws+OFF_WT, ws+OFF_W2, ws+OFF_WI);
    k_conv  <<<dim3(288,3), 192, 0, stream>>>(X, ws+OFF_WT, B1, B2, B3, ws+OFF_U, ws);
    k_stats1<<<1, 192, 0, stream>>>(ws);
    k_inproj<<<dim3(216,3), 256, 0, stream>>>(ws+OFF_U, ws+OFF_XIT, ws+OFF_SZT,
                                              ws+OFF_WI, CW, CB, ws,
                                              G1,BE1,G2,BE2,G3,BE3, LNW,LNB);
    k_xproj <<<dim3(432,3), 256, 0, stream>>>(ws+OFF_XIT, ws+OFF_DTT, ws+OFF_BMT,
                                              ws+OFF_CMT, XPW, DTW, DTB);
    k_scan1 <<<dim3(NCH,2,3), 256, 0, stream>>>(ws+OFF_DTT, ws+OFF_BMT, ws+OFF_XIT,
                                                ALOG, ws+OFF_AGA, ws+OFF_AGB);
    k_scan2 <<<12, 512, 0, stream>>>(ws+OFF_AGA, ws+OFF_AGB, ws+OFF_SEED);
    k_scan3 <<<dim3(NCH,2,3), 256, 0, stream>>>(ws+OFF_DTT, ws+OFF_BMT, ws+OFF_CMT,
                                                ws+OFF_XIT, ws+OFF_SZT, ALOG, DP,
                                                ws+OFF_SEED);
    k_fin   <<<864, 256, 0, stream>>>(ws+OFF_SZT, ws+OFF_W2, BF, ws+OFF_FIN, ws);
    k_statsF<<<1, 64, 0, stream>>>(ws);
    k_out   <<<216, 256, 0, stream>>>(ws+OFF_FIN, ws, GF, BEF, (float*)d_out);
}

// Round 13
// 362.999 us; speedup vs baseline: 1.0391x; 1.0391x over previous
//
#include <hip/hip_runtime.h>

#define LTOT 13824          // 24*24*24
#define NCH 144             // scan chunks
#define CHL 96              // chunk length (144*96 = 13824)
#define EPSF 1e-5f

// ---------- workspace layout (floats) ----------
static const size_t OFF_U   = 1024;                 // conv out; DEAD after inproj
static const size_t NU      = (size_t)3*LTOT*64;    // 2654208
static const size_t NXI     = (size_t)3*LTOT*128;   // 5308416
static const size_t NBM     = (size_t)3*LTOT*16;    // 663552
static const size_t NAG     = (size_t)3*NCH*128*16; // 884736
static const size_t OFF_XIT = OFF_U   + NU;         // xiT[(r*128+i)][l]
static const size_t OFF_SZT = OFF_XIT + NXI;        // szT -> becomes yT in-place
static const size_t OFF_DTT = OFF_SZT + NXI;        // dtT[(r*128+i)][l]
static const size_t OFF_BMT = OFF_DTT + NXI;        // BmT[(r*16+n)][l]
static const size_t OFF_CMT = OFF_BMT + NBM;
static const size_t OFF_W2  = OFF_CMT + NBM;        // 384*64
static const size_t OFF_WT  = OFF_W2 + 24576;       // 3*192*64 transposed conv weights
static const size_t OFF_WI  = OFF_WT + 36864;       // in_proj weights transposed [q][col] 64*256
// scan scratch overlaid on dead U region (3*NAG = 2654208 = NU exactly)
static const size_t OFF_AGA = OFF_U;
static const size_t OFF_AGB = OFF_U + NAG;
static const size_t OFF_SEED= OFF_U + 2*NAG;
static const size_t OFF_FIN = OFF_DTT;              // dtT dead after scan3

__device__ __forceinline__ float sigm(float x){ return 1.f/(1.f+__expf(-x)); }
__device__ __forceinline__ float siluf(float x){ return x*sigm(x); }
__device__ __forceinline__ float softplusf(float x){
    return fmaxf(x,0.f) + log1pf(__expf(-fabsf(x)));
}

// all-VALU cross-lane adds via DPP (no LDS pipe)
template<int CTRL>
__device__ __forceinline__ float dpp_add(float x){
    int v = __builtin_amdgcn_update_dpp(0, __float_as_int(x), CTRL, 0xf, 0xf, true);
    return x + __int_as_float(v);
}
__device__ __forceinline__ float sum16(float x){   // sum within each 16-lane row
    x = dpp_add<0xB1>(x);    // quad_perm xor1
    x = dpp_add<0x4E>(x);    // quad_perm xor2
    x = dpp_add<0x141>(x);   // row_half_mirror
    x = dpp_add<0x140>(x);   // row_mirror
    return x;
}

// ===== K0: weight prep — conv transpose, out_proj∘conv fusion, in_proj^T ===
__global__ __launch_bounds__(256) void k_prep(const float* __restrict__ w1,
                      const float* __restrict__ w2, const float* __restrict__ w3,
                      const float* __restrict__ opw, const float* __restrict__ wf,
                      const float* __restrict__ ipw,
                      float* __restrict__ wt, float* __restrict__ w2t,
                      float* __restrict__ wi)
{
    if (blockIdx.x < 144){
        int idx = blockIdx.x*256 + threadIdx.x;      // 0..36863
        int r = idx / 12288, rem = idx % 12288;
        int k = rem >> 6, o = rem & 63;
        const float* W = (r==0)?w1:(r==1)?w2:w3;
        wt[idx] = W[o*192 + k];
    } else if (blockIdx.x < 240){
        int idx = (blockIdx.x-144)*256 + threadIdx.x; // 0..24575
        int o = idx & 63, ri = idx >> 6;
        int r = ri >> 7, i = ri & 127;
        float acc = 0.f;
        for (int c2=0;c2<64;c2++)
            acc += opw[c2*128+i] * wf[o*192 + r*64 + c2];
        w2t[idx] = acc;
    } else {
        int idx = (blockIdx.x-240)*256 + threadIdx.x; // 0..16383
        int col = idx & 255, q = idx >> 8;
        wi[q*256 + col] = ipw[col*64 + q];
    }
}

// ======= K1: axis conv — 2 rows/block, 4o x 4w, VMEM weights, async-stage ==
// 192 thr = 2 rows x (16og x 6wg); grid (288,3). Stage ph+1 loads under ph.
__global__ __launch_bounds__(192) void k_conv(const float* __restrict__ x,
                       const float* __restrict__ wt,
                       const float* __restrict__ b1, const float* __restrict__ b2,
                       const float* __restrict__ b3,
                       float* __restrict__ u, float* __restrict__ ws)
{
    __shared__ __align__(16) float xs[2*1152];  // x tile only, 9.2 KB
    __shared__ float ssum[64], ssq[64];
    const int r = blockIdx.y;
    const int row0 = blockIdx.x*2;
    const float* Bz = (r==0)?b1:(r==1)?b2:b3;
    const int tid = threadIdx.x;

    if (tid < 64){ ssum[tid]=0.f; ssq[tid]=0.f; }

    const int rw = (tid >= 96) ? 1 : 0, t2 = tid - rw*96;
    const int og = t2 & 15, wg2 = t2 >> 4;      // 16 og x 6 wg
    const int o0 = og*4, w0 = wg2*4;
    float acc[4][4];
    {
        float b0 = Bz[o0], b1v = Bz[o0+1], b2v = Bz[o0+2], b3v = Bz[o0+3];
        #pragma unroll
        for (int wj=0;wj<4;wj++){ acc[0][wj]=b0; acc[1][wj]=b1v; acc[2][wj]=b2v; acc[3][wj]=b3v; }
    }

    // precompute the 12 staging-slot addresses (ph-invariant; ph adds 16*LTOT)
    int sa[12];
    #pragma unroll
    for (int j=0;j<12;j++){
        int f = tid + j*192;               // 0..2303 = rw2*1152 + s
        int rw2 = f / 1152, s = f - rw2*1152;
        int w = s % 24; int kt = s / 24; int ic2 = kt/3, t = kt%3;
        int rr = row0 + rw2;
        int d = rr/24, h = rr%24;
        int src = 0; bool valid = true;
        if (r==0){ int dd = d+t-1; valid = (dd>=0 && dd<24); src = (dd*24+h)*24 + w; }
        else if (r==1){ int hh = h+t-1; valid = (hh>=0 && hh<24); src = (d*24+hh)*24 + w; }
        else { int ww = w+t-1; valid = (ww>=0 && ww<24); src = rr*24 + ww; }
        sa[j] = valid ? (ic2*LTOT + src) : -1;
    }

    const float* xrow = &xs[rw*1152];
    const float* wbase = wt + (size_t)r*12288 + o0;  // per-lane VMEM path

    float rs[12];
    #pragma unroll
    for (int j=0;j<12;j++) rs[j] = (sa[j] >= 0) ? x[sa[j]] : 0.f;

    for (int ph=0; ph<4; ph++){
        __syncthreads();                     // xs free (prev compute done)
        #pragma unroll
        for (int j=0;j<12;j++) xs[tid + j*192] = rs[j];
        if (ph < 3){
            const float* xp = x + (size_t)(ph+1)*16*LTOT;
            #pragma unroll
            for (int j=0;j<12;j++) rs[j] = (sa[j] >= 0) ? xp[sa[j]] : 0.f;
        }
        __syncthreads();                     // xs ready

        for (int sub=0; sub<3; sub++){
            const float* wp = wbase + (size_t)(ph*48 + sub*16)*64;
            float4 wreg[16];
            #pragma unroll
            for (int kk=0;kk<16;kk++)
                wreg[kk] = *(const float4*)&wp[(size_t)kk*64];
            #pragma unroll
            for (int kk=0;kk<16;kk++){
                float4 wv = wreg[kk];
                float4 xv = *(const float4*)&xrow[(sub*16+kk)*24 + w0];
                acc[0][0]=fmaf(wv.x,xv.x,acc[0][0]); acc[0][1]=fmaf(wv.x,xv.y,acc[0][1]);
                acc[0][2]=fmaf(wv.x,xv.z,acc[0][2]); acc[0][3]=fmaf(wv.x,xv.w,acc[0][3]);
                acc[1][0]=fmaf(wv.y,xv.x,acc[1][0]); acc[1][1]=fmaf(wv.y,xv.y,acc[1][1]);
                acc[1][2]=fmaf(wv.y,xv.z,acc[1][2]); acc[1][3]=fmaf(wv.y,xv.w,acc[1][3]);
                acc[2][0]=fmaf(wv.z,xv.x,acc[2][0]); acc[2][1]=fmaf(wv.z,xv.y,acc[2][1]);
                acc[2][2]=fmaf(wv.z,xv.z,acc[2][2]); acc[2][3]=fmaf(wv.z,xv.w,acc[2][3]);
                acc[3][0]=fmaf(wv.w,xv.x,acc[3][0]); acc[3][1]=fmaf(wv.w,xv.y,acc[3][1]);
                acc[3][2]=fmaf(wv.w,xv.z,acc[3][2]); acc[3][3]=fmaf(wv.w,xv.w,acc[3][3]);
            }
        }
    }

    size_t ub = ((size_t)r*LTOT + (size_t)(row0+rw)*24)*64;
    float ps[4]={0,0,0,0}, pq[4]={0,0,0,0};
    #pragma unroll
    for (int wj=0; wj<4; wj++){
        float4 v = make_float4(acc[0][wj],acc[1][wj],acc[2][wj],acc[3][wj]);
        *(float4*)&u[ub + (size_t)(w0+wj)*64 + o0] = v;
        ps[0]+=v.x; pq[0]+=v.x*v.x; ps[1]+=v.y; pq[1]+=v.y*v.y;
        ps[2]+=v.z; pq[2]+=v.z*v.z; ps[3]+=v.w; pq[3]+=v.w*v.w;
    }
    #pragma unroll
    for (int oj=0;oj<4;oj++){
        atomicAdd(&ssum[o0+oj], ps[oj]);
        atomicAdd(&ssq[o0+oj], pq[oj]);
    }
    __syncthreads();
    if (tid < 64){
        atomicAdd(&ws[r*64 + tid], ssum[tid]);
        atomicAdd(&ws[192 + r*64 + tid], ssq[tid]);
    }
}

// ================= K2: finalize branch IN stats ============================
__global__ __launch_bounds__(192) void k_stats1(float* ws){
    int t = threadIdx.x;   // 0..191
    float s = ws[t], q = ws[192+t];
    float m = s*(1.f/(float)LTOT);
    float v = q*(1.f/(float)LTOT) - m*m;
    ws[512+t] = m; ws[704+t] = rsqrtf(v + EPSF);
}

// == K4: fused IN+ReLU+LN + in_proj — 8o x 4p tile, weights in VGPR (VMEM) ==
__global__ __launch_bounds__(256, 2) void k_inproj(const float* __restrict__ u, float* __restrict__ xiT,
                         float* __restrict__ szT, const float* __restrict__ wi,
                         const float* __restrict__ cw, const float* __restrict__ cb,
                         const float* __restrict__ ws,
                         const float* g1,const float* be1,const float* g2,const float* be2,
                         const float* g3,const float* be3,
                         const float* lnw,const float* lnb)
{
    __shared__ float xl[64*65];                 // [c][p] padded, 16.6 KB
    const int tid = threadIdx.x, r = blockIdx.y;
    const int lane = tid & 63;
    const int wv = __builtin_amdgcn_readfirstlane(tid >> 6);
    const int l0 = blockIdx.x*64;
    size_t gbase = (size_t)r*LTOT + l0;

    {
        const float* g  = (r==0)?g1:(r==1)?g2:g3;
        const float* be = (r==0)?be1:(r==1)?be2:be3;
        float m  = ws[512 + r*64 + lane], rs = ws[704 + r*64 + lane];
        float gg = g[lane], bb = be[lane];
        float lw = lnw[lane], lb = lnb[lane];
        for (int j=0;j<16;j++){
            int p = wv*16 + j;
            float vv = u[(gbase+p)*64 + lane];
            vv = fmaxf((vv-m)*rs*gg + bb, 0.f);
            float s1 = sum16(vv), s2 = sum16(vv*vv);
            s1 += __shfl_xor(s1,16); s2 += __shfl_xor(s2,16);
            s1 += __shfl_xor(s1,32); s2 += __shfl_xor(s2,32);
            float mean = s1*(1.f/64.f);
            float var  = s2*(1.f/64.f) - mean*mean;
            xl[lane*65 + p] = (vv-mean)*rsqrtf(var+EPSF)*lw + lb;
        }
    }
    __syncthreads();

    const int pq = tid & 15, oq = tid >> 4;     // 16 p-quads x 16 o-groups
    const int p0 = pq*4;

    #pragma unroll 1
    for (int ch=0; ch<2; ch++){
        const int c0 = ch*128 + oq*8;
        float acc[8][4];
        #pragma unroll
        for (int oj=0;oj<8;oj++){ acc[oj][0]=0.f; acc[oj][1]=0.f; acc[oj][2]=0.f; acc[oj][3]=0.f; }

        for (int sub=0; sub<8; sub++){
            float4 wa[8], wb[8];
            #pragma unroll
            for (int qq=0;qq<8;qq++){
                const float* wp = wi + (size_t)(sub*8+qq)*256 + c0;
                wa[qq] = *(const float4*)wp;
                wb[qq] = *(const float4*)(wp+4);
            }
            #pragma unroll
            for (int qq=0;qq<8;qq++){
                float4 x4 = *(const float4*)&xl[(sub*8+qq)*65 + p0];
                float4 a = wa[qq], b = wb[qq];
                acc[0][0]=fmaf(a.x,x4.x,acc[0][0]); acc[0][1]=fmaf(a.x,x4.y,acc[0][1]);
                acc[0][2]=fmaf(a.x,x4.z,acc[0][2]); acc[0][3]=fmaf(a.x,x4.w,acc[0][3]);
                acc[1][0]=fmaf(a.y,x4.x,acc[1][0]); acc[1][1]=fmaf(a.y,x4.y,acc[1][1]);
                acc[1][2]=fmaf(a.y,x4.z,acc[1][2]); acc[1][3]=fmaf(a.y,x4.w,acc[1][3]);
                acc[2][0]=fmaf(a.z,x4.x,acc[2][0]); acc[2][1]=fmaf(a.z,x4.y,acc[2][1]);
                acc[2][2]=fmaf(a.z,x4.z,acc[2][2]); acc[2][3]=fmaf(a.z,x4.w,acc[2][3]);
                acc[3][0]=fmaf(a.w,x4.x,acc[3][0]); acc[3][1]=fmaf(a.w,x4.y,acc[3][1]);
                acc[3][2]=fmaf(a.w,x4.z,acc[3][2]); acc[3][3]=fmaf(a.w,x4.w,acc[3][3]);
                acc[4][0]=fmaf(b.x,x4.x,acc[4][0]); acc[4][1]=fmaf(b.x,x4.y,acc[4][1]);
                acc[4][2]=fmaf(b.x,x4.z,acc[4][2]); acc[4][3]=fmaf(b.x,x4.w,acc[4][3]);
                acc[5][0]=fmaf(b.y,x4.x,acc[5][0]); acc[5][1]=fmaf(b.y,x4.y,acc[5][1]);
                acc[5][2]=fmaf(b.y,x4.z,acc[5][2]); acc[5][3]=fmaf(b.y,x4.w,acc[5][3]);
                acc[6][0]=fmaf(b.z,x4.x,acc[6][0]); acc[6][1]=fmaf(b.z,x4.y,acc[6][1]);
                acc[6][2]=fmaf(b.z,x4.z,acc[6][2]); acc[6][3]=fmaf(b.z,x4.w,acc[6][3]);
                acc[7][0]=fmaf(b.w,x4.x,acc[7][0]); acc[7][1]=fmaf(b.w,x4.y,acc[7][1]);
                acc[7][2]=fmaf(b.w,x4.z,acc[7][2]); acc[7][3]=fmaf(b.w,x4.w,acc[7][3]);
            }
        }

        if (ch == 0){
            #pragma unroll
            for (int oj=0;oj<8;oj++){
                int c = c0 + oj;
                float cwv = cw[c], cbv = cb[c];
                float4 v = make_float4(
                    siluf(fmaf(acc[oj][0], cwv, cbv)),
                    siluf(fmaf(acc[oj][1], cwv, cbv)),
                    siluf(fmaf(acc[oj][2], cwv, cbv)),
                    siluf(fmaf(acc[oj][3], cwv, cbv)));
                *(float4*)&xiT[((size_t)r*128 + c)*LTOT + l0 + p0] = v;
            }
        } else {
            #pragma unroll
            for (int oj=0;oj<8;oj++){
                int c = c0 - 128 + oj;
                float4 v = make_float4(siluf(acc[oj][0]), siluf(acc[oj][1]),
                                       siluf(acc[oj][2]), siluf(acc[oj][3]));
                *(float4*)&szT[((size_t)r*128 + c)*LTOT + l0 + p0] = v;
            }
        }
    }
}

// ================= K5: x_proj + dt softplus -> transposed rows =============
__global__ __launch_bounds__(256) void k_xproj(const float* __restrict__ xiT, float* __restrict__ dtT,
                        float* __restrict__ BmT, float* __restrict__ CmT,
                        const float* __restrict__ xpw, const float* __restrict__ dtw,
                        const float* __restrict__ dtb)
{
    __shared__ __align__(16) float xt[128*36];   // [c*36 + p]
    __shared__ float ww[36*129];                 // [k*129 + c]
    __shared__ float sd[4*36];                   // dt-rank rows [k*36 + p]
    const int tid = threadIdx.x, r = blockIdx.y;
    const int l0 = blockIdx.x*32;

    for (int s = tid; s < 4096; s += 256){
        int c = s>>5, p = s&31;
        xt[c*36+p] = xiT[((size_t)r*128 + c)*LTOT + l0 + p];
    }
    for (int s = tid; s < 4608; s += 256){
        int k = s>>7, c = s&127;
        ww[k*129+c] = xpw[s];
    }
    __syncthreads();

    const int wv = tid>>6, lane = tid&63;
    float acc[8] = {0,0,0,0,0,0,0,0};
    if (lane < 36){
        const float* wrow = &ww[lane*129];
        for (int c=0;c<128;c++){
            float w = wrow[c];
            float4 a = *(const float4*)&xt[c*36 + wv*8];
            float4 b = *(const float4*)&xt[c*36 + wv*8 + 4];
            acc[0]=fmaf(w,a.x,acc[0]); acc[1]=fmaf(w,a.y,acc[1]);
            acc[2]=fmaf(w,a.z,acc[2]); acc[3]=fmaf(w,a.w,acc[3]);
            acc[4]=fmaf(w,b.x,acc[4]); acc[5]=fmaf(w,b.y,acc[5]);
            acc[6]=fmaf(w,b.z,acc[6]); acc[7]=fmaf(w,b.w,acc[7]);
        }
    }
    if (lane>=4 && lane<36){
        float* dst = (lane<20) ? BmT : CmT;
        int n = (lane<20) ? (lane-4) : (lane-20);
        size_t base = ((size_t)r*16 + n)*LTOT + l0 + wv*8;
        *(float4*)&dst[base]   = make_float4(acc[0],acc[1],acc[2],acc[3]);
        *(float4*)&dst[base+4] = make_float4(acc[4],acc[5],acc[6],acc[7]);
    }
    if (lane < 4){
        #pragma unroll
        for (int p=0;p<8;p++) sd[lane*36 + wv*8 + p] = acc[p];
    }
    __syncthreads();

    const int i = tid>>1, ph = tid&1;
    float4 dw = *(const float4*)&dtw[i*4];
    float db = dtb[i];
    float buf[16];
    #pragma unroll
    for (int t=0;t<16;t++){
        int p = ph*16 + t;
        float v = db + dw.x*sd[0*36+p] + dw.y*sd[1*36+p]
                     + dw.z*sd[2*36+p] + dw.w*sd[3*36+p];
        buf[t] = softplusf(v);
    }
    size_t base = ((size_t)r*128 + i)*LTOT + l0 + ph*16;
    #pragma unroll
    for (int q=0;q<4;q++){
        *(float4*)&dtT[base + 4*q] =
            make_float4(buf[4*q], buf[4*q+1], buf[4*q+2], buf[4*q+3]);
    }
}

// ===== K6: scan pass 1 — quad decomposition, CHL=96, halves of 48 =========
__global__ __launch_bounds__(256) void k_scan1(const float* __restrict__ dtT, const float* __restrict__ BmT,
                        const float* __restrict__ xiT, const float* __restrict__ Alog,
                        float* __restrict__ aga, float* __restrict__ agb)
{
    __shared__ __align__(16) float sdt[64*52];   // 13.3 KB, stride 52
    __shared__ __align__(16) float sxi[64*52];   // 13.3 KB
    __shared__ __align__(16) float sbm[16*52];   //  3.3 KB  -> 29.9 KB total
    const int tid = threadIdx.x;
    const int ng = tid & 3, il = tid >> 2;       // quad = 4 states, il = channel 0..63
    const int c = blockIdx.x, ib = blockIdx.y, r = blockIdx.z;
    const int i = ib*64 + il;

    float A2[4];
    #pragma unroll
    for (int k=0;k<4;k++) A2[k] = -expf(Alog[i*16 + ng*4 + k]) * 1.44269504f;

    const size_t rowDX = ((size_t)r*128 + ib*64)*LTOT + (size_t)c*CHL;
    const size_t rowB  = ((size_t)r*16)*LTOT + (size_t)c*CHL;

    float b0=0.f,b1=0.f,b2=0.f,b3=0.f, dsum=0.f;

    for (int hh=0; hh<2; hh++){
        __syncthreads();
        const int lb = hh*48;
        for (int f = tid; f < 768; f += 256){
            int row = f / 12, t4 = f % 12;
            *(float4*)&sdt[row*52 + t4*4] = *(const float4*)&dtT[rowDX + (size_t)row*LTOT + lb + t4*4];
            *(float4*)&sxi[row*52 + t4*4] = *(const float4*)&xiT[rowDX + (size_t)row*LTOT + lb + t4*4];
        }
        if (tid < 192){
            int row = tid / 12, t4 = tid % 12;
            *(float4*)&sbm[row*52 + t4*4] = *(const float4*)&BmT[rowB + (size_t)row*LTOT + lb + t4*4];
        }
        __syncthreads();

        for (int t4 = 0; t4 < 12; t4++){
            float4 d4 = *(const float4*)&sdt[il*52 + t4*4];
            float4 x4 = *(const float4*)&sxi[il*52 + t4*4];
            float4 B0 = *(const float4*)&sbm[(ng*4+0)*52 + t4*4];
            float4 B1 = *(const float4*)&sbm[(ng*4+1)*52 + t4*4];
            float4 B2 = *(const float4*)&sbm[(ng*4+2)*52 + t4*4];
            float4 B3 = *(const float4*)&sbm[(ng*4+3)*52 + t4*4];
            #define S1Q(dv,xv,c0,c1,c2,c3) { \
                float dx = (dv)*(xv); dsum += (dv); \
                b0 = fmaf(exp2f(A2[0]*(dv)), b0, dx*(c0)); \
                b1 = fmaf(exp2f(A2[1]*(dv)), b1, dx*(c1)); \
                b2 = fmaf(exp2f(A2[2]*(dv)), b2, dx*(c2)); \
                b3 = fmaf(exp2f(A2[3]*(dv)), b3, dx*(c3)); }
            S1Q(d4.x, x4.x, B0.x, B1.x, B2.x, B3.x)
            S1Q(d4.y, x4.y, B0.y, B1.y, B2.y, B3.y)
            S1Q(d4.z, x4.z, B0.z, B1.z, B2.z, B3.z)
            S1Q(d4.w, x4.w, B0.w, B1.w, B2.w, B3.w)
            #undef S1Q
        }
    }

    size_t o = ((size_t)(r*NCH+c)*128 + i)*16 + ng*4;
    *(float4*)&aga[o] = make_float4(exp2f(A2[0]*dsum), exp2f(A2[1]*dsum),
                                    exp2f(A2[2]*dsum), exp2f(A2[3]*dsum));
    *(float4*)&agb[o] = make_float4(b0,b1,b2,b3);
}

// ================= K7: scan pass 2 — combine chunk aggregates ==============
__global__ __launch_bounds__(512) void k_scan2(const float* __restrict__ aga, const float* __restrict__ agb,
                        float* __restrict__ seed)
{
    int t = blockIdx.x*512 + threadIdx.x;  // 0..6143
    int r = t >> 11, rem = t & 2047;
    float h = 0.f;
    for (int c=0;c<NCH;c++){
        size_t idx = (size_t)(r*NCH+c)*2048 + rem;
        float a = aga[idx], b = agb[idx];
        seed[idx] = h;
        h = fmaf(a, h, b);
    }
}

// ===== K8: scan pass 3 — quad replay, CHL=96, halves of 48 =================
__global__ __launch_bounds__(256) void k_scan3(const float* __restrict__ dtT, const float* __restrict__ BmT,
                        const float* __restrict__ CmT, const float* __restrict__ xiT,
                        float* __restrict__ szT, const float* __restrict__ Alog,
                        const float* __restrict__ Dp, const float* __restrict__ seed)
{
    __shared__ __align__(16) float sdt[64*52];   // 13.3 KB; y_raw overwrites in place
    __shared__ __align__(16) float sxi[64*52];   // 13.3 KB
    __shared__ __align__(16) float sbm[16*52];   //  3.3 KB
    __shared__ __align__(16) float scm[16*52];   //  3.3 KB  -> 32.5 KB total
    const int tid = threadIdx.x;
    const int ng = tid & 3, il = tid >> 2;
    const int c = blockIdx.x, ib = blockIdx.y, r = blockIdx.z;
    const int i = ib*64 + il;

    float A2[4];
    #pragma unroll
    for (int k=0;k<4;k++) A2[k] = -expf(Alog[i*16 + ng*4 + k]) * 1.44269504f;
    const float Dv = Dp[i];

    float4 h4 = *(const float4*)&seed[((size_t)(r*NCH+c)*128 + i)*16 + ng*4];
    float h0=h4.x, h1=h4.y, h2=h4.z, h3=h4.w;

    const size_t rowDX = ((size_t)r*128 + ib*64)*LTOT + (size_t)c*CHL;
    const size_t rowB  = ((size_t)r*16)*LTOT + (size_t)c*CHL;

    for (int hh=0; hh<2; hh++){
        __syncthreads();           // guard against previous half's write-back reads
        const int lb = hh*48;
        for (int f = tid; f < 768; f += 256){
            int row = f / 12, t4 = f % 12;
            *(float4*)&sdt[row*52 + t4*4] = *(const float4*)&dtT[rowDX + (size_t)row*LTOT + lb + t4*4];
            *(float4*)&sxi[row*52 + t4*4] = *(const float4*)&xiT[rowDX + (size_t)row*LTOT + lb + t4*4];
        }
        for (int f = tid; f < 384; f += 256){
            int arr = f / 192, f2 = f % 192;
            int row = f2 / 12, t4 = f2 % 12;
            if (arr == 0)
                *(float4*)&sbm[row*52 + t4*4] = *(const float4*)&BmT[rowB + (size_t)row*LTOT + lb + t4*4];
            else
                *(float4*)&scm[row*52 + t4*4] = *(const float4*)&CmT[rowB + (size_t)row*LTOT + lb + t4*4];
        }
        __syncthreads();

        for (int t4 = 0; t4 < 12; t4++){
            float4 d4 = *(const float4*)&sdt[il*52 + t4*4];
            float4 x4 = *(const float4*)&sxi[il*52 + t4*4];
            float4 B0 = *(const float4*)&sbm[(ng*4+0)*52 + t4*4];
            float4 B1 = *(const float4*)&sbm[(ng*4+1)*52 + t4*4];
            float4 B2 = *(const float4*)&sbm[(ng*4+2)*52 + t4*4];
            float4 B3 = *(const float4*)&sbm[(ng*4+3)*52 + t4*4];
            float4 C0 = *(const float4*)&scm[(ng*4+0)*52 + t4*4];
            float4 C1 = *(const float4*)&scm[(ng*4+1)*52 + t4*4];
            float4 C2 = *(const float4*)&scm[(ng*4+2)*52 + t4*4];
            float4 C3 = *(const float4*)&scm[(ng*4+3)*52 + t4*4];
            float4 y4;
            #define S3Q(dv,xv,b0c,b1c,b2c,b3c,c0c,c1c,c2c,c3c,oy) { \
                float dx = (dv)*(xv); \
                h0 = fmaf(exp2f(A2[0]*(dv)), h0, dx*(b0c)); \
                h1 = fmaf(exp2f(A2[1]*(dv)), h1, dx*(b1c)); \
                h2 = fmaf(exp2f(A2[2]*(dv)), h2, dx*(b2c)); \
                h3 = fmaf(exp2f(A2[3]*(dv)), h3, dx*(b3c)); \
                float p = h0*(c0c); p = fmaf(h1,(c1c),p); \
                p = fmaf(h2,(c2c),p); p = fmaf(h3,(c3c),p); \
                p = dpp_add<0xB1>(p); p = dpp_add<0x4E>(p); \
                oy = fmaf((xv), Dv, p); }
            S3Q(d4.x,x4.x, B0.x,B1.x,B2.x,B3.x, C0.x,C1.x,C2.x,C3.x, y4.x)
            S3Q(d4.y,x4.y, B0.y,B1.y,B2.y,B3.y, C0.y,C1.y,C2.y,C3.y, y4.y)
            S3Q(d4.z,x4.z, B0.z,B1.z,B2.z,B3.z, C0.z,C1.z,C2.z,C3.z, y4.z)
            S3Q(d4.w,x4.w, B0.w,B1.w,B2.w,B3.w, C0.w,C1.w,C2.w,C3.w, y4.w)
            #undef S3Q
            if (ng == 0) *(float4*)&sdt[il*52 + t4*4] = y4;   // y_raw into consumed dt slot
        }
        __syncthreads();

        // coalesced write-back: y_raw * sz -> szT (in place)
        for (int f = tid; f < 768; f += 256){
            int row = f / 12, t4 = f % 12;
            size_t gidx = rowDX + (size_t)row*LTOT + lb + t4*4;
            float4 yv = *(const float4*)&sdt[row*52 + t4*4];
            float4 s  = *(const float4*)&szT[gidx];
            *(float4*)&szT[gidx] = make_float4(yv.x*s.x, yv.y*s.y, yv.z*s.z, yv.w*s.w);
        }
    }
}

// ========== K10: out_proj∘conv GEMM — w in VGPRs, float4 y-staging =========
__global__ __launch_bounds__(256, 1) void k_fin(const float* __restrict__ yT, const float* __restrict__ w2t,
                      const float* __restrict__ bfb, float* __restrict__ fin,
                      float* __restrict__ ws)
{
    __shared__ __align__(16) float yl[384*20];  // [k*20 + p], 30.7 KB
    __shared__ float part[4*16*64];             // [sg][p][o], 16 KB
    __shared__ float ssum[64], ssq[64];
    const int tid = threadIdx.x;
    const int l0 = blockIdx.x*16;
    const int o = tid & 63, sg = tid >> 6;

    // float4 staging: 6 rounds/thread (was 24 scalar)
    for (int f = tid; f < 1536; f += 256){
        int k = f >> 2, pq = f & 3;
        *(float4*)&yl[k*20 + pq*4] =
            *(const float4*)&yT[(size_t)k*LTOT + l0 + pq*4];
    }
    float wreg[96];
    {
        const float* wp = w2t + (size_t)(sg*96)*64 + o;
        #pragma unroll
        for (int j=0;j<96;j++) wreg[j] = wp[(size_t)j*64];
    }
    if (tid < 64){ ssum[tid]=0.f; ssq[tid]=0.f; }
    __syncthreads();

    float acc[16];
    #pragma unroll
    for (int p=0;p<16;p++) acc[p]=0.f;
    const float* ylbase = &yl[sg*96*20];
    #pragma unroll
    for (int j=0;j<96;j++){
        float w = wreg[j];
        const float4* yp4 = (const float4*)&ylbase[j*20];
        float4 a = yp4[0], b = yp4[1], c = yp4[2], d = yp4[3];
        acc[0] =fmaf(w,a.x,acc[0]);  acc[1] =fmaf(w,a.y,acc[1]);
        acc[2] =fmaf(w,a.z,acc[2]);  acc[3] =fmaf(w,a.w,acc[3]);
        acc[4] =fmaf(w,b.x,acc[4]);  acc[5] =fmaf(w,b.y,acc[5]);
        acc[6] =fmaf(w,b.z,acc[6]);  acc[7] =fmaf(w,b.w,acc[7]);
        acc[8] =fmaf(w,c.x,acc[8]);  acc[9] =fmaf(w,c.y,acc[9]);
        acc[10]=fmaf(w,c.z,acc[10]); acc[11]=fmaf(w,c.w,acc[11]);
        acc[12]=fmaf(w,d.x,acc[12]); acc[13]=fmaf(w,d.y,acc[13]);
        acc[14]=fmaf(w,d.z,acc[14]); acc[15]=fmaf(w,d.w,acc[15]);
    }
    #pragma unroll
    for (int p=0;p<16;p++) part[(sg*16+p)*64 + o] = acc[p];
    __syncthreads();

    float bias = bfb[o];
    float ps=0.f, pq=0.f;
    #pragma unroll
    for (int j=0;j<4;j++){
        int p = sg + j*4;
        float s = part[(0*16+p)*64+o] + part[(1*16+p)*64+o]
                + part[(2*16+p)*64+o] + part[(3*16+p)*64+o] + bias;
        fin[(size_t)(l0+p)*64 + o] = s;
        ps += s; pq += s*s;
    }
    atomicAdd(&ssum[o], ps); atomicAdd(&ssq[o], pq);
    __syncthreads();
    if (tid<64){
        atomicAdd(&ws[384+tid], ssum[tid]);
        atomicAdd(&ws[448+tid], ssq[tid]);
    }
}

// ================= K11: finalize final IN stats ============================
__global__ __launch_bounds__(64) void k_statsF(float* ws){
    int t = threadIdx.x;  // 0..63
    float s = ws[384+t], q = ws[448+t];
    float m = s*(1.f/(float)LTOT);
    float v = q*(1.f/(float)LTOT) - m*m;
    ws[896+t] = m; ws[960+t] = rsqrtf(v + EPSF);
}

// ================= K12: final IN + ReLU + transpose + fp32 store ===========
__global__ __launch_bounds__(256) void k_out(const float* __restrict__ fin, const float* __restrict__ ws,
                      const float* __restrict__ gf, const float* __restrict__ bef,
                      float* __restrict__ out)
{
    __shared__ float tl[64*65];
    const int tid = threadIdx.x;
    const int l0 = blockIdx.x*64;
    for (int s=tid; s<4096; s+=256){
        int li = s>>6, o = s&63;
        float v = fin[(size_t)(l0+li)*64 + o];
        v = fmaxf((v - ws[896+o])*ws[960+o]*gf[o] + bef[o], 0.f);
        tl[o*65+li] = v;
    }
    __syncthreads();
    for (int s=tid; s<4096; s+=256){
        int o = s>>6, li = s&63;
        out[(size_t)o*LTOT + l0 + li] = tl[o*65+li];
    }
}

extern "C" void kernel_launch(void* const* d_in, const int* in_sizes, int n_in,
                              void* d_out, int out_size, void* d_ws, size_t ws_size,
                              hipStream_t stream)
{
    const float* X    = (const float*)d_in[0];
    const float* W1   = (const float*)d_in[1];  const float* B1  = (const float*)d_in[2];
    const float* G1   = (const float*)d_in[3];  const float* BE1 = (const float*)d_in[4];
    const float* W2   = (const float*)d_in[5];  const float* B2  = (const float*)d_in[6];
    const float* G2   = (const float*)d_in[7];  const float* BE2 = (const float*)d_in[8];
    const float* W3   = (const float*)d_in[9];  const float* B3  = (const float*)d_in[10];
    const float* G3   = (const float*)d_in[11]; const float* BE3 = (const float*)d_in[12];
    const float* LNW  = (const float*)d_in[13]; const float* LNB = (const float*)d_in[14];
    const float* IPW  = (const float*)d_in[15];
    const float* CW   = (const float*)d_in[16]; const float* CB  = (const float*)d_in[17];
    const float* XPW  = (const float*)d_in[18];
    const float* DTW  = (const float*)d_in[19]; const float* DTB = (const float*)d_in[20];
    const float* ALOG = (const float*)d_in[21]; const float* DP  = (const float*)d_in[22];
    const float* OPW  = (const float*)d_in[23];
    const float* WF   = (const float*)d_in[24]; const float* BF  = (const float*)d_in[25];
    const float* GF   = (const float*)d_in[26]; const float* BEF = (const float*)d_in[27];
    float* ws = (float*)d_ws;

    (void)hipMemsetAsync(d_ws, 0, 2048, stream);

    k_prep  <<<304, 256, 0, stream>>>(W1, W2, W3, OPW, WF, IPW,
                                      ws+OFF_WT, ws+OFF_W2, ws+OFF_WI);
    k_conv  <<<dim3(288,3), 192, 0, stream>>>(X, ws+OFF_WT, B1, B2, B3, ws+OFF_U, ws);
    k_stats1<<<1, 192, 0, stream>>>(ws);
    k_inproj<<<dim3(216,3), 256, 0, stream>>>(ws+OFF_U, ws+OFF_XIT, ws+OFF_SZT,
                                              ws+OFF_WI, CW, CB, ws,
                                              G1,BE1,G2,BE2,G3,BE3, LNW,LNB);
    k_xproj <<<dim3(432,3), 256, 0, stream>>>(ws+OFF_XIT, ws+OFF_DTT, ws+OFF_BMT,
                                              ws+OFF_CMT, XPW, DTW, DTB);
    k_scan1 <<<dim3(NCH,2,3), 256, 0, stream>>>(ws+OFF_DTT, ws+OFF_BMT, ws+OFF_XIT,
                                                ALOG, ws+OFF_AGA, ws+OFF_AGB);
    k_scan2 <<<12, 512, 0, stream>>>(ws+OFF_AGA, ws+OFF_AGB, ws+OFF_SEED);
    k_scan3 <<<dim3(NCH,2,3), 256, 0, stream>>>(ws+OFF_DTT, ws+OFF_BMT, ws+OFF_CMT,
                                                ws+OFF_XIT, ws+OFF_SZT, ALOG, DP,
                                                ws+OFF_SEED);
    k_fin   <<<864, 256, 0, stream>>>(ws+OFF_SZT, ws+OFF_W2, BF, ws+OFF_FIN, ws);
    k_statsF<<<1, 64, 0, stream>>>(ws);
    k_out   <<<216, 256, 0, stream>>>(ws+OFF_FIN, ws, GF, BEF, (float*)d_out);
}

// Round 14
// 356.360 us; speedup vs baseline: 1.0585x; 1.0186x over previous
//
#include <hip/hip_runtime.h>

#define LTOT 13824          // 24*24*24
#define NCH 144             // scan chunks
#define CHL 96              // chunk length (144*96 = 13824)
#define EPSF 1e-5f

// ---------- workspace layout (floats) ----------
static const size_t OFF_U   = 1024;                 // conv out; DEAD after inproj
static const size_t NU      = (size_t)3*LTOT*64;    // 2654208
static const size_t NXI     = (size_t)3*LTOT*128;   // 5308416
static const size_t NBM     = (size_t)3*LTOT*16;    // 663552
static const size_t NAG     = (size_t)3*NCH*128*16; // 884736
static const size_t OFF_XIT = OFF_U   + NU;         // xiT[(r*128+i)][l]
static const size_t OFF_SZT = OFF_XIT + NXI;        // szT -> becomes yT in-place
static const size_t OFF_DTT = OFF_SZT + NXI;        // dtT[(r*128+i)][l]
static const size_t OFF_BMT = OFF_DTT + NXI;        // BmT[(r*16+n)][l]
static const size_t OFF_CMT = OFF_BMT + NBM;
static const size_t OFF_W2  = OFF_CMT + NBM;        // 384*64
static const size_t OFF_WT  = OFF_W2 + 24576;       // 3*192*64 transposed conv weights
static const size_t OFF_WI  = OFF_WT + 36864;       // in_proj weights transposed [q][col] 64*256
// scan scratch overlaid on dead U region (3*NAG = 2654208 = NU exactly)
static const size_t OFF_AGA = OFF_U;
static const size_t OFF_AGB = OFF_U + NAG;
static const size_t OFF_SEED= OFF_U + 2*NAG;
static const size_t OFF_FIN = OFF_DTT;              // dtT dead after scan3

__device__ __forceinline__ float sigm(float x){ return 1.f/(1.f+__expf(-x)); }
__device__ __forceinline__ float siluf(float x){ return x*sigm(x); }
__device__ __forceinline__ float softplusf(float x){
    return fmaxf(x,0.f) + log1pf(__expf(-fabsf(x)));
}

// all-VALU cross-lane adds via DPP (no LDS pipe)
template<int CTRL>
__device__ __forceinline__ float dpp_add(float x){
    int v = __builtin_amdgcn_update_dpp(0, __float_as_int(x), CTRL, 0xf, 0xf, true);
    return x + __int_as_float(v);
}
__device__ __forceinline__ float sum16(float x){   // sum within each 16-lane row
    x = dpp_add<0xB1>(x);    // quad_perm xor1
    x = dpp_add<0x4E>(x);    // quad_perm xor2
    x = dpp_add<0x141>(x);   // row_half_mirror
    x = dpp_add<0x140>(x);   // row_mirror
    return x;
}

// ===== K0: weight prep — conv transpose, out_proj∘conv fusion, in_proj^T ===
__global__ __launch_bounds__(256) void k_prep(const float* __restrict__ w1,
                      const float* __restrict__ w2, const float* __restrict__ w3,
                      const float* __restrict__ opw, const float* __restrict__ wf,
                      const float* __restrict__ ipw,
                      float* __restrict__ wt, float* __restrict__ w2t,
                      float* __restrict__ wi)
{
    if (blockIdx.x < 144){
        int idx = blockIdx.x*256 + threadIdx.x;      // 0..36863
        int r = idx / 12288, rem = idx % 12288;
        int k = rem >> 6, o = rem & 63;
        const float* W = (r==0)?w1:(r==1)?w2:w3;
        wt[idx] = W[o*192 + k];
    } else if (blockIdx.x < 240){
        int idx = (blockIdx.x-144)*256 + threadIdx.x; // 0..24575
        int o = idx & 63, ri = idx >> 6;
        int r = ri >> 7, i = ri & 127;
        float acc = 0.f;
        for (int c2=0;c2<64;c2++)
            acc += opw[c2*128+i] * wf[o*192 + r*64 + c2];
        w2t[idx] = acc;
    } else {
        int idx = (blockIdx.x-240)*256 + threadIdx.x; // 0..16383
        int col = idx & 255, q = idx >> 8;
        wi[q*256 + col] = ipw[col*64 + q];
    }
}

// ======= K1: axis conv — 2 rows/block, 4o x 4w, VMEM weights, async-stage ==
// 192 thr = 2 rows x (16og x 6wg); grid (288,3). Stage ph+1 loads under ph.
__global__ __launch_bounds__(192) void k_conv(const float* __restrict__ x,
                       const float* __restrict__ wt,
                       const float* __restrict__ b1, const float* __restrict__ b2,
                       const float* __restrict__ b3,
                       float* __restrict__ u, float* __restrict__ ws)
{
    __shared__ __align__(16) float xs[2*1152];  // x tile only, 9.2 KB
    __shared__ float ssum[64], ssq[64];
    const int r = blockIdx.y;
    const int row0 = blockIdx.x*2;
    const float* Bz = (r==0)?b1:(r==1)?b2:b3;
    const int tid = threadIdx.x;

    if (tid < 64){ ssum[tid]=0.f; ssq[tid]=0.f; }

    const int rw = (tid >= 96) ? 1 : 0, t2 = tid - rw*96;
    const int og = t2 & 15, wg2 = t2 >> 4;      // 16 og x 6 wg
    const int o0 = og*4, w0 = wg2*4;
    float acc[4][4];
    {
        float b0 = Bz[o0], b1v = Bz[o0+1], b2v = Bz[o0+2], b3v = Bz[o0+3];
        #pragma unroll
        for (int wj=0;wj<4;wj++){ acc[0][wj]=b0; acc[1][wj]=b1v; acc[2][wj]=b2v; acc[3][wj]=b3v; }
    }

    // precompute the 12 staging-slot addresses (ph-invariant; ph adds 16*LTOT)
    int sa[12];
    #pragma unroll
    for (int j=0;j<12;j++){
        int f = tid + j*192;               // 0..2303 = rw2*1152 + s
        int rw2 = f / 1152, s = f - rw2*1152;
        int w = s % 24; int kt = s / 24; int ic2 = kt/3, t = kt%3;
        int rr = row0 + rw2;
        int d = rr/24, h = rr%24;
        int src = 0; bool valid = true;
        if (r==0){ int dd = d+t-1; valid = (dd>=0 && dd<24); src = (dd*24+h)*24 + w; }
        else if (r==1){ int hh = h+t-1; valid = (hh>=0 && hh<24); src = (d*24+hh)*24 + w; }
        else { int ww = w+t-1; valid = (ww>=0 && ww<24); src = rr*24 + ww; }
        sa[j] = valid ? (ic2*LTOT + src) : -1;
    }

    const float* xrow = &xs[rw*1152];
    const float* wbase = wt + (size_t)r*12288 + o0;  // per-lane VMEM path

    float rs[12];
    #pragma unroll
    for (int j=0;j<12;j++) rs[j] = (sa[j] >= 0) ? x[sa[j]] : 0.f;

    for (int ph=0; ph<4; ph++){
        __syncthreads();                     // xs free (prev compute done)
        #pragma unroll
        for (int j=0;j<12;j++) xs[tid + j*192] = rs[j];
        if (ph < 3){
            const float* xp = x + (size_t)(ph+1)*16*LTOT;
            #pragma unroll
            for (int j=0;j<12;j++) rs[j] = (sa[j] >= 0) ? xp[sa[j]] : 0.f;
        }
        __syncthreads();                     // xs ready

        for (int sub=0; sub<3; sub++){
            const float* wp = wbase + (size_t)(ph*48 + sub*16)*64;
            float4 wreg[16];
            #pragma unroll
            for (int kk=0;kk<16;kk++)
                wreg[kk] = *(const float4*)&wp[(size_t)kk*64];
            #pragma unroll
            for (int kk=0;kk<16;kk++){
                float4 wv = wreg[kk];
                float4 xv = *(const float4*)&xrow[(sub*16+kk)*24 + w0];
                acc[0][0]=fmaf(wv.x,xv.x,acc[0][0]); acc[0][1]=fmaf(wv.x,xv.y,acc[0][1]);
                acc[0][2]=fmaf(wv.x,xv.z,acc[0][2]); acc[0][3]=fmaf(wv.x,xv.w,acc[0][3]);
                acc[1][0]=fmaf(wv.y,xv.x,acc[1][0]); acc[1][1]=fmaf(wv.y,xv.y,acc[1][1]);
                acc[1][2]=fmaf(wv.y,xv.z,acc[1][2]); acc[1][3]=fmaf(wv.y,xv.w,acc[1][3]);
                acc[2][0]=fmaf(wv.z,xv.x,acc[2][0]); acc[2][1]=fmaf(wv.z,xv.y,acc[2][1]);
                acc[2][2]=fmaf(wv.z,xv.z,acc[2][2]); acc[2][3]=fmaf(wv.z,xv.w,acc[2][3]);
                acc[3][0]=fmaf(wv.w,xv.x,acc[3][0]); acc[3][1]=fmaf(wv.w,xv.y,acc[3][1]);
                acc[3][2]=fmaf(wv.w,xv.z,acc[3][2]); acc[3][3]=fmaf(wv.w,xv.w,acc[3][3]);
            }
        }
    }

    size_t ub = ((size_t)r*LTOT + (size_t)(row0+rw)*24)*64;
    float ps[4]={0,0,0,0}, pq[4]={0,0,0,0};
    #pragma unroll
    for (int wj=0; wj<4; wj++){
        float4 v = make_float4(acc[0][wj],acc[1][wj],acc[2][wj],acc[3][wj]);
        *(float4*)&u[ub + (size_t)(w0+wj)*64 + o0] = v;
        ps[0]+=v.x; pq[0]+=v.x*v.x; ps[1]+=v.y; pq[1]+=v.y*v.y;
        ps[2]+=v.z; pq[2]+=v.z*v.z; ps[3]+=v.w; pq[3]+=v.w*v.w;
    }
    #pragma unroll
    for (int oj=0;oj<4;oj++){
        atomicAdd(&ssum[o0+oj], ps[oj]);
        atomicAdd(&ssq[o0+oj], pq[oj]);
    }
    __syncthreads();
    if (tid < 64){
        atomicAdd(&ws[r*64 + tid], ssum[tid]);
        atomicAdd(&ws[192 + r*64 + tid], ssq[tid]);
    }
}

// ================= K2: finalize branch IN stats ============================
__global__ __launch_bounds__(192) void k_stats1(float* ws){
    int t = threadIdx.x;   // 0..191
    float s = ws[t], q = ws[192+t];
    float m = s*(1.f/(float)LTOT);
    float v = q*(1.f/(float)LTOT) - m*m;
    ws[512+t] = m; ws[704+t] = rsqrtf(v + EPSF);
}

// == K4: fused IN+ReLU+LN + in_proj — 8o x 4p tile, weights in VGPR (VMEM) ==
__global__ __launch_bounds__(256, 2) void k_inproj(const float* __restrict__ u, float* __restrict__ xiT,
                         float* __restrict__ szT, const float* __restrict__ wi,
                         const float* __restrict__ cw, const float* __restrict__ cb,
                         const float* __restrict__ ws,
                         const float* g1,const float* be1,const float* g2,const float* be2,
                         const float* g3,const float* be3,
                         const float* lnw,const float* lnb)
{
    __shared__ float xl[64*65];                 // [c][p] padded, 16.6 KB
    const int tid = threadIdx.x, r = blockIdx.y;
    const int lane = tid & 63;
    const int wv = __builtin_amdgcn_readfirstlane(tid >> 6);
    const int l0 = blockIdx.x*64;
    size_t gbase = (size_t)r*LTOT + l0;

    {
        const float* g  = (r==0)?g1:(r==1)?g2:g3;
        const float* be = (r==0)?be1:(r==1)?be2:be3;
        float m  = ws[512 + r*64 + lane], rs = ws[704 + r*64 + lane];
        float gg = g[lane], bb = be[lane];
        float lw = lnw[lane], lb = lnb[lane];
        for (int j=0;j<16;j++){
            int p = wv*16 + j;
            float vv = u[(gbase+p)*64 + lane];
            vv = fmaxf((vv-m)*rs*gg + bb, 0.f);
            float s1 = sum16(vv), s2 = sum16(vv*vv);
            s1 += __shfl_xor(s1,16); s2 += __shfl_xor(s2,16);
            s1 += __shfl_xor(s1,32); s2 += __shfl_xor(s2,32);
            float mean = s1*(1.f/64.f);
            float var  = s2*(1.f/64.f) - mean*mean;
            xl[lane*65 + p] = (vv-mean)*rsqrtf(var+EPSF)*lw + lb;
        }
    }
    __syncthreads();

    const int pq = tid & 15, oq = tid >> 4;     // 16 p-quads x 16 o-groups
    const int p0 = pq*4;

    #pragma unroll 1
    for (int ch=0; ch<2; ch++){
        const int c0 = ch*128 + oq*8;
        float acc[8][4];
        #pragma unroll
        for (int oj=0;oj<8;oj++){ acc[oj][0]=0.f; acc[oj][1]=0.f; acc[oj][2]=0.f; acc[oj][3]=0.f; }

        for (int sub=0; sub<8; sub++){
            float4 wa[8], wb[8];
            #pragma unroll
            for (int qq=0;qq<8;qq++){
                const float* wp = wi + (size_t)(sub*8+qq)*256 + c0;
                wa[qq] = *(const float4*)wp;
                wb[qq] = *(const float4*)(wp+4);
            }
            #pragma unroll
            for (int qq=0;qq<8;qq++){
                float4 x4 = *(const float4*)&xl[(sub*8+qq)*65 + p0];
                float4 a = wa[qq], b = wb[qq];
                acc[0][0]=fmaf(a.x,x4.x,acc[0][0]); acc[0][1]=fmaf(a.x,x4.y,acc[0][1]);
                acc[0][2]=fmaf(a.x,x4.z,acc[0][2]); acc[0][3]=fmaf(a.x,x4.w,acc[0][3]);
                acc[1][0]=fmaf(a.y,x4.x,acc[1][0]); acc[1][1]=fmaf(a.y,x4.y,acc[1][1]);
                acc[1][2]=fmaf(a.y,x4.z,acc[1][2]); acc[1][3]=fmaf(a.y,x4.w,acc[1][3]);
                acc[2][0]=fmaf(a.z,x4.x,acc[2][0]); acc[2][1]=fmaf(a.z,x4.y,acc[2][1]);
                acc[2][2]=fmaf(a.z,x4.z,acc[2][2]); acc[2][3]=fmaf(a.z,x4.w,acc[2][3]);
                acc[3][0]=fmaf(a.w,x4.x,acc[3][0]); acc[3][1]=fmaf(a.w,x4.y,acc[3][1]);
                acc[3][2]=fmaf(a.w,x4.z,acc[3][2]); acc[3][3]=fmaf(a.w,x4.w,acc[3][3]);
                acc[4][0]=fmaf(b.x,x4.x,acc[4][0]); acc[4][1]=fmaf(b.x,x4.y,acc[4][1]);
                acc[4][2]=fmaf(b.x,x4.z,acc[4][2]); acc[4][3]=fmaf(b.x,x4.w,acc[4][3]);
                acc[5][0]=fmaf(b.y,x4.x,acc[5][0]); acc[5][1]=fmaf(b.y,x4.y,acc[5][1]);
                acc[5][2]=fmaf(b.y,x4.z,acc[5][2]); acc[5][3]=fmaf(b.y,x4.w,acc[5][3]);
                acc[6][0]=fmaf(b.z,x4.x,acc[6][0]); acc[6][1]=fmaf(b.z,x4.y,acc[6][1]);
                acc[6][2]=fmaf(b.z,x4.z,acc[6][2]); acc[6][3]=fmaf(b.z,x4.w,acc[6][3]);
                acc[7][0]=fmaf(b.w,x4.x,acc[7][0]); acc[7][1]=fmaf(b.w,x4.y,acc[7][1]);
                acc[7][2]=fmaf(b.w,x4.z,acc[7][2]); acc[7][3]=fmaf(b.w,x4.w,acc[7][3]);
            }
        }

        if (ch == 0){
            #pragma unroll
            for (int oj=0;oj<8;oj++){
                int c = c0 + oj;
                float cwv = cw[c], cbv = cb[c];
                float4 v = make_float4(
                    siluf(fmaf(acc[oj][0], cwv, cbv)),
                    siluf(fmaf(acc[oj][1], cwv, cbv)),
                    siluf(fmaf(acc[oj][2], cwv, cbv)),
                    siluf(fmaf(acc[oj][3], cwv, cbv)));
                *(float4*)&xiT[((size_t)r*128 + c)*LTOT + l0 + p0] = v;
            }
        } else {
            #pragma unroll
            for (int oj=0;oj<8;oj++){
                int c = c0 - 128 + oj;
                float4 v = make_float4(siluf(acc[oj][0]), siluf(acc[oj][1]),
                                       siluf(acc[oj][2]), siluf(acc[oj][3]));
                *(float4*)&szT[((size_t)r*128 + c)*LTOT + l0 + p0] = v;
            }
        }
    }
}

// ================= K5: x_proj + dt softplus -> transposed rows =============
__global__ __launch_bounds__(256) void k_xproj(const float* __restrict__ xiT, float* __restrict__ dtT,
                        float* __restrict__ BmT, float* __restrict__ CmT,
                        const float* __restrict__ xpw, const float* __restrict__ dtw,
                        const float* __restrict__ dtb)
{
    __shared__ __align__(16) float xt[128*36];   // [c*36 + p]
    __shared__ float ww[36*129];                 // [k*129 + c]
    __shared__ float sd[4*36];                   // dt-rank rows [k*36 + p]
    const int tid = threadIdx.x, r = blockIdx.y;
    const int l0 = blockIdx.x*32;

    for (int s = tid; s < 4096; s += 256){
        int c = s>>5, p = s&31;
        xt[c*36+p] = xiT[((size_t)r*128 + c)*LTOT + l0 + p];
    }
    for (int s = tid; s < 4608; s += 256){
        int k = s>>7, c = s&127;
        ww[k*129+c] = xpw[s];
    }
    __syncthreads();

    const int wv = tid>>6, lane = tid&63;
    float acc[8] = {0,0,0,0,0,0,0,0};
    if (lane < 36){
        const float* wrow = &ww[lane*129];
        for (int c=0;c<128;c++){
            float w = wrow[c];
            float4 a = *(const float4*)&xt[c*36 + wv*8];
            float4 b = *(const float4*)&xt[c*36 + wv*8 + 4];
            acc[0]=fmaf(w,a.x,acc[0]); acc[1]=fmaf(w,a.y,acc[1]);
            acc[2]=fmaf(w,a.z,acc[2]); acc[3]=fmaf(w,a.w,acc[3]);
            acc[4]=fmaf(w,b.x,acc[4]); acc[5]=fmaf(w,b.y,acc[5]);
            acc[6]=fmaf(w,b.z,acc[6]); acc[7]=fmaf(w,b.w,acc[7]);
        }
    }
    if (lane>=4 && lane<36){
        float* dst = (lane<20) ? BmT : CmT;
        int n = (lane<20) ? (lane-4) : (lane-20);
        size_t base = ((size_t)r*16 + n)*LTOT + l0 + wv*8;
        *(float4*)&dst[base]   = make_float4(acc[0],acc[1],acc[2],acc[3]);
        *(float4*)&dst[base+4] = make_float4(acc[4],acc[5],acc[6],acc[7]);
    }
    if (lane < 4){
        #pragma unroll
        for (int p=0;p<8;p++) sd[lane*36 + wv*8 + p] = acc[p];
    }
    __syncthreads();

    const int i = tid>>1, ph = tid&1;
    float4 dw = *(const float4*)&dtw[i*4];
    float db = dtb[i];
    float buf[16];
    #pragma unroll
    for (int t=0;t<16;t++){
        int p = ph*16 + t;
        float v = db + dw.x*sd[0*36+p] + dw.y*sd[1*36+p]
                     + dw.z*sd[2*36+p] + dw.w*sd[3*36+p];
        buf[t] = softplusf(v);
    }
    size_t base = ((size_t)r*128 + i)*LTOT + l0 + ph*16;
    #pragma unroll
    for (int q=0;q<4;q++){
        *(float4*)&dtT[base + 4*q] =
            make_float4(buf[4*q], buf[4*q+1], buf[4*q+2], buf[4*q+3]);
    }
}

// ===== K6: scan pass 1 — quad decomposition, CHL=96, halves of 48 =========
__global__ __launch_bounds__(256) void k_scan1(const float* __restrict__ dtT, const float* __restrict__ BmT,
                        const float* __restrict__ xiT, const float* __restrict__ Alog,
                        float* __restrict__ aga, float* __restrict__ agb)
{
    __shared__ __align__(16) float sdt[64*52];   // 13.3 KB, stride 52
    __shared__ __align__(16) float sxi[64*52];   // 13.3 KB
    __shared__ __align__(16) float sbm[16*52];   //  3.3 KB  -> 29.9 KB total
    const int tid = threadIdx.x;
    const int ng = tid & 3, il = tid >> 2;       // quad = 4 states, il = channel 0..63
    const int c = blockIdx.x, ib = blockIdx.y, r = blockIdx.z;
    const int i = ib*64 + il;

    float A2[4];
    #pragma unroll
    for (int k=0;k<4;k++) A2[k] = -expf(Alog[i*16 + ng*4 + k]) * 1.44269504f;

    const size_t rowDX = ((size_t)r*128 + ib*64)*LTOT + (size_t)c*CHL;
    const size_t rowB  = ((size_t)r*16)*LTOT + (size_t)c*CHL;

    float b0=0.f,b1=0.f,b2=0.f,b3=0.f, dsum=0.f;

    for (int hh=0; hh<2; hh++){
        __syncthreads();
        const int lb = hh*48;
        for (int f = tid; f < 768; f += 256){
            int row = f / 12, t4 = f % 12;
            *(float4*)&sdt[row*52 + t4*4] = *(const float4*)&dtT[rowDX + (size_t)row*LTOT + lb + t4*4];
            *(float4*)&sxi[row*52 + t4*4] = *(const float4*)&xiT[rowDX + (size_t)row*LTOT + lb + t4*4];
        }
        if (tid < 192){
            int row = tid / 12, t4 = tid % 12;
            *(float4*)&sbm[row*52 + t4*4] = *(const float4*)&BmT[rowB + (size_t)row*LTOT + lb + t4*4];
        }
        __syncthreads();

        for (int t4 = 0; t4 < 12; t4++){
            float4 d4 = *(const float4*)&sdt[il*52 + t4*4];
            float4 x4 = *(const float4*)&sxi[il*52 + t4*4];
            float4 B0 = *(const float4*)&sbm[(ng*4+0)*52 + t4*4];
            float4 B1 = *(const float4*)&sbm[(ng*4+1)*52 + t4*4];
            float4 B2 = *(const float4*)&sbm[(ng*4+2)*52 + t4*4];
            float4 B3 = *(const float4*)&sbm[(ng*4+3)*52 + t4*4];
            #define S1Q(dv,xv,c0,c1,c2,c3) { \
                float dx = (dv)*(xv); dsum += (dv); \
                b0 = fmaf(exp2f(A2[0]*(dv)), b0, dx*(c0)); \
                b1 = fmaf(exp2f(A2[1]*(dv)), b1, dx*(c1)); \
                b2 = fmaf(exp2f(A2[2]*(dv)), b2, dx*(c2)); \
                b3 = fmaf(exp2f(A2[3]*(dv)), b3, dx*(c3)); }
            S1Q(d4.x, x4.x, B0.x, B1.x, B2.x, B3.x)
            S1Q(d4.y, x4.y, B0.y, B1.y, B2.y, B3.y)
            S1Q(d4.z, x4.z, B0.z, B1.z, B2.z, B3.z)
            S1Q(d4.w, x4.w, B0.w, B1.w, B2.w, B3.w)
            #undef S1Q
        }
    }

    size_t o = ((size_t)(r*NCH+c)*128 + i)*16 + ng*4;
    *(float4*)&aga[o] = make_float4(exp2f(A2[0]*dsum), exp2f(A2[1]*dsum),
                                    exp2f(A2[2]*dsum), exp2f(A2[3]*dsum));
    *(float4*)&agb[o] = make_float4(b0,b1,b2,b3);
}

// ================= K7: scan pass 2 — combine chunk aggregates ==============
__global__ __launch_bounds__(512) void k_scan2(const float* __restrict__ aga, const float* __restrict__ agb,
                        float* __restrict__ seed)
{
    int t = blockIdx.x*512 + threadIdx.x;  // 0..6143
    int r = t >> 11, rem = t & 2047;
    float h = 0.f;
    for (int c=0;c<NCH;c++){
        size_t idx = (size_t)(r*NCH+c)*2048 + rem;
        float a = aga[idx], b = agb[idx];
        seed[idx] = h;
        h = fmaf(a, h, b);
    }
}

// ===== K8: scan pass 3 — quad replay, CHL=96, halves of 48 =================
__global__ __launch_bounds__(256) void k_scan3(const float* __restrict__ dtT, const float* __restrict__ BmT,
                        const float* __restrict__ CmT, const float* __restrict__ xiT,
                        float* __restrict__ szT, const float* __restrict__ Alog,
                        const float* __restrict__ Dp, const float* __restrict__ seed)
{
    __shared__ __align__(16) float sdt[64*52];   // 13.3 KB; y_raw overwrites in place
    __shared__ __align__(16) float sxi[64*52];   // 13.3 KB
    __shared__ __align__(16) float sbm[16*52];   //  3.3 KB
    __shared__ __align__(16) float scm[16*52];   //  3.3 KB  -> 32.5 KB total
    const int tid = threadIdx.x;
    const int ng = tid & 3, il = tid >> 2;
    const int c = blockIdx.x, ib = blockIdx.y, r = blockIdx.z;
    const int i = ib*64 + il;

    float A2[4];
    #pragma unroll
    for (int k=0;k<4;k++) A2[k] = -expf(Alog[i*16 + ng*4 + k]) * 1.44269504f;
    const float Dv = Dp[i];

    float4 h4 = *(const float4*)&seed[((size_t)(r*NCH+c)*128 + i)*16 + ng*4];
    float h0=h4.x, h1=h4.y, h2=h4.z, h3=h4.w;

    const size_t rowDX = ((size_t)r*128 + ib*64)*LTOT + (size_t)c*CHL;
    const size_t rowB  = ((size_t)r*16)*LTOT + (size_t)c*CHL;

    for (int hh=0; hh<2; hh++){
        __syncthreads();           // guard against previous half's write-back reads
        const int lb = hh*48;
        for (int f = tid; f < 768; f += 256){
            int row = f / 12, t4 = f % 12;
            *(float4*)&sdt[row*52 + t4*4] = *(const float4*)&dtT[rowDX + (size_t)row*LTOT + lb + t4*4];
            *(float4*)&sxi[row*52 + t4*4] = *(const float4*)&xiT[rowDX + (size_t)row*LTOT + lb + t4*4];
        }
        for (int f = tid; f < 384; f += 256){
            int arr = f / 192, f2 = f % 192;
            int row = f2 / 12, t4 = f2 % 12;
            if (arr == 0)
                *(float4*)&sbm[row*52 + t4*4] = *(const float4*)&BmT[rowB + (size_t)row*LTOT + lb + t4*4];
            else
                *(float4*)&scm[row*52 + t4*4] = *(const float4*)&CmT[rowB + (size_t)row*LTOT + lb + t4*4];
        }
        __syncthreads();

        for (int t4 = 0; t4 < 12; t4++){
            float4 d4 = *(const float4*)&sdt[il*52 + t4*4];
            float4 x4 = *(const float4*)&sxi[il*52 + t4*4];
            float4 B0 = *(const float4*)&sbm[(ng*4+0)*52 + t4*4];
            float4 B1 = *(const float4*)&sbm[(ng*4+1)*52 + t4*4];
            float4 B2 = *(const float4*)&sbm[(ng*4+2)*52 + t4*4];
            float4 B3 = *(const float4*)&sbm[(ng*4+3)*52 + t4*4];
            float4 C0 = *(const float4*)&scm[(ng*4+0)*52 + t4*4];
            float4 C1 = *(const float4*)&scm[(ng*4+1)*52 + t4*4];
            float4 C2 = *(const float4*)&scm[(ng*4+2)*52 + t4*4];
            float4 C3 = *(const float4*)&scm[(ng*4+3)*52 + t4*4];
            float4 y4;
            #define S3Q(dv,xv,b0c,b1c,b2c,b3c,c0c,c1c,c2c,c3c,oy) { \
                float dx = (dv)*(xv); \
                h0 = fmaf(exp2f(A2[0]*(dv)), h0, dx*(b0c)); \
                h1 = fmaf(exp2f(A2[1]*(dv)), h1, dx*(b1c)); \
                h2 = fmaf(exp2f(A2[2]*(dv)), h2, dx*(b2c)); \
                h3 = fmaf(exp2f(A2[3]*(dv)), h3, dx*(b3c)); \
                float p = h0*(c0c); p = fmaf(h1,(c1c),p); \
                p = fmaf(h2,(c2c),p); p = fmaf(h3,(c3c),p); \
                p = dpp_add<0xB1>(p); p = dpp_add<0x4E>(p); \
                oy = fmaf((xv), Dv, p); }
            S3Q(d4.x,x4.x, B0.x,B1.x,B2.x,B3.x, C0.x,C1.x,C2.x,C3.x, y4.x)
            S3Q(d4.y,x4.y, B0.y,B1.y,B2.y,B3.y, C0.y,C1.y,C2.y,C3.y, y4.y)
            S3Q(d4.z,x4.z, B0.z,B1.z,B2.z,B3.z, C0.z,C1.z,C2.z,C3.z, y4.z)
            S3Q(d4.w,x4.w, B0.w,B1.w,B2.w,B3.w, C0.w,C1.w,C2.w,C3.w, y4.w)
            #undef S3Q
            if (ng == 0) *(float4*)&sdt[il*52 + t4*4] = y4;   // y_raw into consumed dt slot
        }
        __syncthreads();

        // coalesced write-back: y_raw * sz -> szT (in place)
        for (int f = tid; f < 768; f += 256){
            int row = f / 12, t4 = f % 12;
            size_t gidx = rowDX + (size_t)row*LTOT + lb + t4*4;
            float4 yv = *(const float4*)&sdt[row*52 + t4*4];
            float4 s  = *(const float4*)&szT[gidx];
            *(float4*)&szT[gidx] = make_float4(yv.x*s.x, yv.y*s.y, yv.z*s.z, yv.w*s.w);
        }
    }
}

// ========== K10: out_proj∘conv GEMM — w fully unrolled into VGPRs ==========
__global__ __launch_bounds__(256, 1) void k_fin(const float* __restrict__ yT, const float* __restrict__ w2t,
                      const float* __restrict__ bfb, float* __restrict__ fin,
                      float* __restrict__ ws)
{
    __shared__ __align__(16) float yl[384*20];  // [k*20 + p], 30.7 KB
    __shared__ float part[4*16*64];             // [sg][p][o], 16 KB
    __shared__ float ssum[64], ssq[64];
    const int tid = threadIdx.x;
    const int l0 = blockIdx.x*16;
    const int o = tid & 63, sg = tid >> 6;

    for (int f = tid; f < 6144; f += 256){
        int k = f >> 4, p = f & 15;
        yl[k*20 + p] = yT[(size_t)k*LTOT + l0 + p];
    }
    float wreg[96];
    {
        const float* wp = w2t + (size_t)(sg*96)*64 + o;
        #pragma unroll
        for (int j=0;j<96;j++) wreg[j] = wp[(size_t)j*64];
    }
    if (tid < 64){ ssum[tid]=0.f; ssq[tid]=0.f; }
    __syncthreads();

    float acc[16];
    #pragma unroll
    for (int p=0;p<16;p++) acc[p]=0.f;
    const float* ylbase = &yl[sg*96*20];
    #pragma unroll
    for (int j=0;j<96;j++){
        float w = wreg[j];
        const float4* yp4 = (const float4*)&ylbase[j*20];
        float4 a = yp4[0], b = yp4[1], c = yp4[2], d = yp4[3];
        acc[0] =fmaf(w,a.x,acc[0]);  acc[1] =fmaf(w,a.y,acc[1]);
        acc[2] =fmaf(w,a.z,acc[2]);  acc[3] =fmaf(w,a.w,acc[3]);
        acc[4] =fmaf(w,b.x,acc[4]);  acc[5] =fmaf(w,b.y,acc[5]);
        acc[6] =fmaf(w,b.z,acc[6]);  acc[7] =fmaf(w,b.w,acc[7]);
        acc[8] =fmaf(w,c.x,acc[8]);  acc[9] =fmaf(w,c.y,acc[9]);
        acc[10]=fmaf(w,c.z,acc[10]); acc[11]=fmaf(w,c.w,acc[11]);
        acc[12]=fmaf(w,d.x,acc[12]); acc[13]=fmaf(w,d.y,acc[13]);
        acc[14]=fmaf(w,d.z,acc[14]); acc[15]=fmaf(w,d.w,acc[15]);
    }
    #pragma unroll
    for (int p=0;p<16;p++) part[(sg*16+p)*64 + o] = acc[p];
    __syncthreads();

    float bias = bfb[o];
    float ps=0.f, pq=0.f;
    #pragma unroll
    for (int j=0;j<4;j++){
        int p = sg + j*4;
        float s = part[(0*16+p)*64+o] + part[(1*16+p)*64+o]
                + part[(2*16+p)*64+o] + part[(3*16+p)*64+o] + bias;
        fin[(size_t)(l0+p)*64 + o] = s;
        ps += s; pq += s*s;
    }
    atomicAdd(&ssum[o], ps); atomicAdd(&ssq[o], pq);
    __syncthreads();
    if (tid<64){
        atomicAdd(&ws[384+tid], ssum[tid]);
        atomicAdd(&ws[448+tid], ssq[tid]);
    }
}

// ================= K11: finalize final IN stats ============================
__global__ __launch_bounds__(64) void k_statsF(float* ws){
    int t = threadIdx.x;  // 0..63
    float s = ws[384+t], q = ws[448+t];
    float m = s*(1.f/(float)LTOT);
    float v = q*(1.f/(float)LTOT) - m*m;
    ws[896+t] = m; ws[960+t] = rsqrtf(v + EPSF);
}

// ================= K12: final IN + ReLU + transpose + fp32 store ===========
__global__ __launch_bounds__(256) void k_out(const float* __restrict__ fin, const float* __restrict__ ws,
                      const float* __restrict__ gf, const float* __restrict__ bef,
                      float* __restrict__ out)
{
    __shared__ float tl[64*65];
    const int tid = threadIdx.x;
    const int l0 = blockIdx.x*64;
    for (int s=tid; s<4096; s+=256){
        int li = s>>6, o = s&63;
        float v = fin[(size_t)(l0+li)*64 + o];
        v = fmaxf((v - ws[896+o])*ws[960+o]*gf[o] + bef[o], 0.f);
        tl[o*65+li] = v;
    }
    __syncthreads();
    for (int s=tid; s<4096; s+=256){
        int o = s>>6, li = s&63;
        out[(size_t)o*LTOT + l0 + li] = tl[o*65+li];
    }
}

extern "C" void kernel_launch(void* const* d_in, const int* in_sizes, int n_in,
                              void* d_out, int out_size, void* d_ws, size_t ws_size,
                              hipStream_t stream)
{
    const float* X    = (const float*)d_in[0];
    const float* W1   = (const float*)d_in[1];  const float* B1  = (const float*)d_in[2];
    const float* G1   = (const float*)d_in[3];  const float* BE1 = (const float*)d_in[4];
    const float* W2   = (const float*)d_in[5];  const float* B2  = (const float*)d_in[6];
    const float* G2   = (const float*)d_in[7];  const float* BE2 = (const float*)d_in[8];
    const float* W3   = (const float*)d_in[9];  const float* B3  = (const float*)d_in[10];
    const float* G3   = (const float*)d_in[11]; const float* BE3 = (const float*)d_in[12];
    const float* LNW  = (const float*)d_in[13]; const float* LNB = (const float*)d_in[14];
    const float* IPW  = (const float*)d_in[15];
    const float* CW   = (const float*)d_in[16]; const float* CB  = (const float*)d_in[17];
    const float* XPW  = (const float*)d_in[18];
    const float* DTW  = (const float*)d_in[19]; const float* DTB = (const float*)d_in[20];
    const float* ALOG = (const float*)d_in[21]; const float* DP  = (const float*)d_in[22];
    const float* OPW  = (const float*)d_in[23];
    const float* WF   = (const float*)d_in[24]; const float* BF  = (const float*)d_in[25];
    const float* GF   = (const float*)d_in[26]; const float* BEF = (const float*)d_in[27];
    float* ws = (float*)d_ws;

    (void)hipMemsetAsync(d_ws, 0, 2048, stream);

    k_prep  <<<304, 256, 0, stream>>>(W1, W2, W3, OPW, WF, IPW,
                                      ws+OFF_WT, ws+OFF_W2, ws+OFF_WI);
    k_conv  <<<dim3(288,3), 192, 0, stream>>>(X, ws+OFF_WT, B1, B2, B3, ws+OFF_U, ws);
    k_stats1<<<1, 192, 0, stream>>>(ws);
    k_inproj<<<dim3(216,3), 256, 0, stream>>>(ws+OFF_U, ws+OFF_XIT, ws+OFF_SZT,
                                              ws+OFF_WI, CW, CB, ws,
                                              G1,BE1,G2,BE2,G3,BE3, LNW,LNB);
    k_xproj <<<dim3(432,3), 256, 0, stream>>>(ws+OFF_XIT, ws+OFF_DTT, ws+OFF_BMT,
                                              ws+OFF_CMT, XPW, DTW, DTB);
    k_scan1 <<<dim3(NCH,2,3), 256, 0, stream>>>(ws+OFF_DTT, ws+OFF_BMT, ws+OFF_XIT,
                                                ALOG, ws+OFF_AGA, ws+OFF_AGB);
    k_scan2 <<<12, 512, 0, stream>>>(ws+OFF_AGA, ws+OFF_AGB, ws+OFF_SEED);
    k_scan3 <<<dim3(NCH,2,3), 256, 0, stream>>>(ws+OFF_DTT, ws+OFF_BMT, ws+OFF_CMT,
                                                ws+OFF_XIT, ws+OFF_SZT, ALOG, DP,
                                                ws+OFF_SEED);
    k_fin   <<<864, 256, 0, stream>>>(ws+OFF_SZT, ws+OFF_W2, BF, ws+OFF_FIN, ws);
    k_statsF<<<1, 64, 0, stream>>>(ws);
    k_out   <<<216, 256, 0, stream>>>(ws+OFF_FIN, ws, GF, BEF, (float*)d_out);
}